// Round 2
// baseline (3974.653 us; speedup 1.0000x reference)
//
#include <hip/hip_runtime.h>
#include <math.h>

#define B_ 128
#define L_ 200
#define C_ 300
#define K_ 128
#define A_ 5000
#define F_ 64
#define D_ 512   // K * 4 branches
#define KC_ (K_*C_)   // 38400

// ---------------- workspace layout (floats) ----------------
#define OFF_WTT   ((size_t)0)                       // 537600 repacked conv weights
#define OFF_E     ((size_t)537600)                  // B*D = 65536
#define OFF_UST   (OFF_E + (size_t)B_*D_)           // B*F = 8192
#define OFF_VB    (OFF_UST + (size_t)B_*F_)         // 64
#define OFF_S2    (OFF_VB + 64)                     // 128
#define OFF_T     (OFF_S2 + 128)                    // 5120 (pad)
#define OFF_UM    (OFF_T + 5120)                    // B*2A = 1,280,000
#define OFF_UF    (OFF_UM + (size_t)B_*2*A_)        // B*2A = 1,280,000
#define OFF_UMMF  (OFF_UF + (size_t)B_*2*A_)        // B*A  = 640,000
#define OFF_PART  (OFF_UMMF + (size_t)B_*A_)        // 8*B*A = 5,120,000

// ---------------- conv weight repack: [k][c][w] -> branch-major [k][w][c] ----
__global__ void repack_kernel(const float* __restrict__ w2, const float* __restrict__ w3,
                              const float* __restrict__ w4, const float* __restrict__ w5,
                              float* __restrict__ wtT)
{
    int idx = blockIdx.x * 256 + threadIdx.x;
    int off, ws; const float* src;
    if (idx < KC_*2)       { off = idx;           ws = 2; src = w2; }
    else if (idx < KC_*5)  { off = idx - KC_*2;   ws = 3; src = w3; }
    else if (idx < KC_*9)  { off = idx - KC_*5;   ws = 4; src = w4; }
    else if (idx < KC_*14) { off = idx - KC_*9;   ws = 5; src = w5; }
    else return;
    int k = off / (ws * C_);
    int r = off % (ws * C_);
    int w = r / C_;
    int c = r % C_;
    wtT[idx] = src[(k * C_ + c) * ws + w];
}

// ---------------- TextCNN conv + relu + max-pool -> e (B, 512) ----------------
// grid: (32 kgroups, 4 branches, 128 batch), block: 64 (one wave)
__global__ __launch_bounds__(64) void conv_max_kernel(
    const float* __restrict__ x, const float* __restrict__ wtT,
    const float* __restrict__ b2, const float* __restrict__ b3,
    const float* __restrict__ b4, const float* __restrict__ b5,
    float* __restrict__ e)
{
    const int kg = blockIdx.x;      // 0..31
    const int wi = blockIdx.y;      // 0..3
    const int b  = blockIdx.z;      // 0..127
    const int lane = threadIdx.x;   // 0..63
    const int k0 = kg * 4;
    const int ws = wi + 2;
    const int Pout = L_ - ws + 1;

    const int base = (wi == 0) ? 0 : (wi == 1) ? KC_*2 : (wi == 2) ? KC_*5 : KC_*9;
    const float* wt = wtT + base + (size_t)k0 * ws * C_;   // [kk][w][c]
    const float* biasp = (wi == 0) ? b2 : (wi == 1) ? b3 : (wi == 2) ? b4 : b5;
    const float bias0 = biasp[k0+0], bias1 = biasp[k0+1];
    const float bias2v = biasp[k0+2], bias3v = biasp[k0+3];

    const float* xb = x + (size_t)b * L_ * C_;

    float m0 = 0.f, m1 = 0.f, m2 = 0.f, m3 = 0.f;

    for (int p = lane; p < Pout; p += 64) {
        float a0 = bias0, a1 = bias1, a2 = bias2v, a3 = bias3v;
        for (int w = 0; w < ws; ++w) {
            const float4* xr  = (const float4*)(xb + (size_t)(p + w) * C_);
            const float4* wr0 = (const float4*)(wt + (size_t)(0*ws + w) * C_);
            const float4* wr1 = (const float4*)(wt + (size_t)(1*ws + w) * C_);
            const float4* wr2 = (const float4*)(wt + (size_t)(2*ws + w) * C_);
            const float4* wr3 = (const float4*)(wt + (size_t)(3*ws + w) * C_);
            for (int c4 = 0; c4 < C_/4; ++c4) {
                const float4 xv = xr[c4];
                const float4 v0 = wr0[c4];
                a0 += xv.x*v0.x + xv.y*v0.y + xv.z*v0.z + xv.w*v0.w;
                const float4 v1 = wr1[c4];
                a1 += xv.x*v1.x + xv.y*v1.y + xv.z*v1.z + xv.w*v1.w;
                const float4 v2 = wr2[c4];
                a2 += xv.x*v2.x + xv.y*v2.y + xv.z*v2.z + xv.w*v2.w;
                const float4 v3 = wr3[c4];
                a3 += xv.x*v3.x + xv.y*v3.y + xv.z*v3.z + xv.w*v3.w;
            }
        }
        m0 = fmaxf(m0, a0); m1 = fmaxf(m1, a1);
        m2 = fmaxf(m2, a2); m3 = fmaxf(m3, a3);
    }
    // wave max-reduce (64 lanes)
    for (int d = 1; d < 64; d <<= 1) {
        m0 = fmaxf(m0, __shfl_xor(m0, d));
        m1 = fmaxf(m1, __shfl_xor(m1, d));
        m2 = fmaxf(m2, __shfl_xor(m2, d));
        m3 = fmaxf(m3, __shfl_xor(m3, d));
    }
    if (lane == 0) {
        float* eb = e + (size_t)b * D_;
        eb[(k0+0)*4 + wi] = m0;
        eb[(k0+1)*4 + wi] = m1;
        eb[(k0+2)*4 + wi] = m2;
        eb[(k0+3)*4 + wi] = m3;
    }
}

// ---------------- generic out = in @ W^T, j-split partials ----------------
// grid: (ceil(N/256), B/32, JS), block 256.  jper MUST be a multiple of 4.
__global__ __launch_bounds__(256) void gemm_bt_kernel(
    const float* __restrict__ in, int ldin,
    const float* __restrict__ W, int kdim, int N, int jper,
    float* __restrict__ partial)
{
    const int n  = blockIdx.x * 256 + threadIdx.x;
    const int b0 = blockIdx.y * 32;
    const int jlo = blockIdx.z * jper;
    const int jhi = min(jlo + jper, kdim);
    if (n >= N) return;

    float acc[32];
    #pragma unroll
    for (int i = 0; i < 32; ++i) acc[i] = 0.f;

    const float* wr = W + (size_t)n * kdim;
    for (int j = jlo; j < jhi; j += 4) {
        const float4 w4 = *(const float4*)(wr + j);
        #pragma unroll
        for (int bi = 0; bi < 32; ++bi) {
            const float4 iv = *(const float4*)(in + (size_t)(b0 + bi) * ldin + j);
            acc[bi] += w4.x*iv.x + w4.y*iv.y + w4.z*iv.z + w4.w*iv.w;
        }
    }
    const size_t base = ((size_t)blockIdx.z * B_ + b0) * N + n;
    #pragma unroll
    for (int bi = 0; bi < 32; ++bi)
        partial[base + (size_t)bi * N] = acc[bi];
}

// sum partials + bias (+ optional tanh) -> out[b*ldo + ooff + n]
__global__ void reduce_kernel(const float* __restrict__ partial, const float* __restrict__ bias,
                              float* __restrict__ out, int N, int ldo, int ooff, int js, int act)
{
    const int idx = blockIdx.x * 256 + threadIdx.x;
    if (idx >= B_ * N) return;
    const int n = idx % N;
    const int b = idx / N;
    float s = bias[n];
    for (int k = 0; k < js; ++k) s += partial[(size_t)k * B_ * N + idx];
    if (act) s = tanhf(s);
    out[(size_t)b * ldo + ooff + n] = s;
}

// ---------------- tiny precompute: vA,vB,c,s2 ----------------
__global__ void prep_kernel(const float* __restrict__ mlp_w1, const float* __restrict__ mlp_b1,
                            const float* __restrict__ mlp_w2, const float* __restrict__ mlp_b2,
                            const float* __restrict__ ust,
                            float* __restrict__ vB, float* __restrict__ s2)
{
    __shared__ float vA[64];
    __shared__ float csh;
    const int tid = threadIdx.x;   // 128 threads
    if (tid < 64) {
        float a = 0.f;
        for (int f = 0; f < 64; ++f) a += mlp_w2[f] * mlp_w1[f * 128 + tid];
        vA[tid] = a;
    } else {
        const int g = tid - 64;
        float bsum = 0.f;
        for (int f = 0; f < 64; ++f) bsum += mlp_w2[f] * mlp_w1[f * 128 + 64 + g];
        vB[g] = bsum;
    }
    if (tid == 0) {
        float c = mlp_b2[0];
        for (int f = 0; f < 64; ++f) c += mlp_b1[f] * mlp_w2[f];
        csh = c;
    }
    __syncthreads();
    float s = csh;
    const float* ub = ust + (size_t)tid * F_;
    for (int g = 0; g < 64; ++g) s += ub[g] * vA[g];
    s2[tid] = s;
}

// t[a] = sum_g emb[g,a] * vB[g]
__global__ void ta_kernel(const float* __restrict__ emb, const float* __restrict__ vB,
                          float* __restrict__ t)
{
    __shared__ float v[64];
    if (threadIdx.x < 64) v[threadIdx.x] = vB[threadIdx.x];
    __syncthreads();
    const int a = blockIdx.x * 256 + threadIdx.x;
    if (a < A_) {
        float acc = 0.f;
        #pragma unroll
        for (int g = 0; g < 64; ++g) acc += v[g] * emb[(size_t)g * A_ + a];
        t[a] = acc;
    }
}

// um[b, :A] = ust[b] @ emb ; um[b, A+a] = tanh(s2[b] + t[a])
__global__ void um_kernel(const float* __restrict__ ust, const float* __restrict__ emb,
                          const float* __restrict__ s2, const float* __restrict__ t,
                          float* __restrict__ um)
{
    const int b = blockIdx.y;
    __shared__ float us[64];
    if (threadIdx.x < 64) us[threadIdx.x] = ust[(size_t)b * F_ + threadIdx.x];
    __syncthreads();
    const int a = blockIdx.x * 256 + threadIdx.x;
    if (a < A_) {
        float acc = 0.f;
        #pragma unroll
        for (int g = 0; g < 64; ++g) acc += us[g] * emb[(size_t)g * A_ + a];
        um[(size_t)b * (2*A_) + a] = acc;
        um[(size_t)b * (2*A_) + A_ + a] = tanhf(s2[b] + t[a]);
    }
}

// ---------------- launch ----------------
extern "C" void kernel_launch(void* const* d_in, const int* in_sizes, int n_in,
                              void* d_out, int out_size, void* d_ws, size_t ws_size,
                              hipStream_t stream)
{
    const float* x       = (const float*)d_in[0];
    const float* conv_w2 = (const float*)d_in[1];
    const float* conv_b2 = (const float*)d_in[2];
    const float* conv_w3 = (const float*)d_in[3];
    const float* conv_b3 = (const float*)d_in[4];
    const float* conv_w4 = (const float*)d_in[5];
    const float* conv_b4 = (const float*)d_in[6];
    const float* conv_w5 = (const float*)d_in[7];
    const float* conv_b5 = (const float*)d_in[8];
    const float* sc_fcl_w = (const float*)d_in[9];
    const float* sc_fcl_b = (const float*)d_in[10];
    const float* fic_fc_w = (const float*)d_in[11];
    const float* fic_fc_b = (const float*)d_in[12];
    const float* emb      = (const float*)d_in[13];
    const float* mlp_w1   = (const float*)d_in[14];
    const float* mlp_b1   = (const float*)d_in[15];
    const float* mlp_w2   = (const float*)d_in[16];
    const float* mlp_b2   = (const float*)d_in[17];
    const float* fic_fcl_w = (const float*)d_in[18];
    const float* fic_fcl_b = (const float*)d_in[19];
    const float* fusion_w  = (const float*)d_in[20];
    const float* fusion_b  = (const float*)d_in[21];
    const float* task_w    = (const float*)d_in[22];
    const float* task_b    = (const float*)d_in[23];

    float* ws = (float*)d_ws;
    float* wtT  = ws + OFF_WTT;
    float* e    = ws + OFF_E;
    float* ust  = ws + OFF_UST;
    float* vB   = ws + OFF_VB;
    float* s2   = ws + OFF_S2;
    float* t    = ws + OFF_T;
    float* um   = ws + OFF_UM;
    float* uf   = ws + OFF_UF;
    float* ummf = ws + OFF_UMMF;
    float* part = ws + OFF_PART;

    float* out = (float*)d_out;

    // 1. repack conv weights
    repack_kernel<<<(KC_*14 + 255)/256, 256, 0, stream>>>(conv_w2, conv_w3, conv_w4, conv_w5, wtT);

    // 2. conv + relu + maxpool -> e
    conv_max_kernel<<<dim3(32, 4, 128), 64, 0, stream>>>(x, wtT, conv_b2, conv_b3, conv_b4, conv_b5, e);

    // 3. u_sc = e @ sc_fcl_w^T + b -> uf[:, :A]
    gemm_bt_kernel<<<dim3(20, 4, 1), 256, 0, stream>>>(e, D_, sc_fcl_w, D_, A_, D_, part);
    reduce_kernel<<<(B_*A_ + 255)/256, 256, 0, stream>>>(part, sc_fcl_b, uf, A_, 2*A_, 0, 1, 0);

    // 4. ust = e @ fic_fc_w^T + b
    gemm_bt_kernel<<<dim3(1, 4, 1), 256, 0, stream>>>(e, D_, fic_fc_w, D_, F_, D_, part);
    reduce_kernel<<<(B_*F_ + 255)/256, 256, 0, stream>>>(part, fic_fc_b, ust, F_, F_, 0, 1, 0);

    // 5. vA/vB/c/s2
    prep_kernel<<<1, 128, 0, stream>>>(mlp_w1, mlp_b1, mlp_w2, mlp_b2, ust, vB, s2);

    // 6. t[a]
    ta_kernel<<<(A_ + 255)/256, 256, 0, stream>>>(emb, vB, t);

    // 7. um = [u_mm | u_mlp]
    um_kernel<<<dim3((A_ + 255)/256, B_), 256, 0, stream>>>(ust, emb, s2, t, um);

    // 8. u_fic = tanh(um @ fic_fcl_w^T + b) -> uf[:, A:]   (jper=1256, 8 splits, last=1208)
    gemm_bt_kernel<<<dim3(20, 4, 8), 256, 0, stream>>>(um, 2*A_, fic_fcl_w, 2*A_, A_, 1256, part);
    reduce_kernel<<<(B_*A_ + 255)/256, 256, 0, stream>>>(part, fic_fcl_b, uf, A_, 2*A_, A_, 8, 1);

    // 9. u_mmf = uf @ fusion_w^T + b   (jper=1256, 8 splits)
    gemm_bt_kernel<<<dim3(20, 4, 8), 256, 0, stream>>>(uf, 2*A_, fusion_w, 2*A_, A_, 1256, part);
    reduce_kernel<<<(B_*A_ + 255)/256, 256, 0, stream>>>(part, fusion_b, ummf, A_, A_, 0, 8, 0);

    // 10. task = u_mmf @ task_w^T + b -> out   (jper=1252, 4 splits, last=1244)
    gemm_bt_kernel<<<dim3(20, 4, 4), 256, 0, stream>>>(ummf, A_, task_w, A_, A_, 1252, part);
    reduce_kernel<<<(B_*A_ + 255)/256, 256, 0, stream>>>(part, task_b, out, A_, A_, 0, 4, 0);
}

// Round 3
// 649.786 us; speedup vs baseline: 6.1169x; 6.1169x over previous
//
#include <hip/hip_runtime.h>
#include <math.h>

#define B_ 128
#define L_ 200
#define C_ 300
#define K_ 128
#define A_ 5000
#define F_ 64
#define D_ 512
#define CP_ 320      // padded C (multiple of 32)
#define LP_ 260      // padded L rows for conv A-tiles (256 + 4)
#define NPAD_ 5056   // 79*64

typedef __attribute__((ext_vector_type(8))) short bf16x8;
typedef __attribute__((ext_vector_type(8))) short short8;
typedef __attribute__((ext_vector_type(4))) short short4v;
typedef __attribute__((ext_vector_type(4))) float f32x4;

#define MFMA(a,b,c) __builtin_amdgcn_mfma_f32_16x16x32_bf16(a,b,c,0,0,0)

static __device__ __forceinline__ unsigned short f2bf(float f) {
    unsigned u = __float_as_uint(f);
    unsigned r = (u + 0x7FFFu + ((u >> 16) & 1u)) >> 16;
    return (unsigned short)r;
}

// ---------------- workspace layout (float offsets) ----------------
// R0 region (floats 0..5,324,800) multiplexed over time:
//   phase conv: xp (bf16 [128][260][320] = 10,649,600 shorts)
//   phase gemm: PART/UM at 0 ; UMBF@2,588,672 ; UFBF@3,229,696 ; UMMFBF@3,870,720
//               UMMF aliases UMBF slot after fic gemm consumed UMBF.
#define OFF_XP    ((size_t)0)
#define OFF_PART  ((size_t)0)
#define OFF_UM    ((size_t)0)
#define OFF_UMBF  ((size_t)2588672)
#define OFF_UMMF  ((size_t)2588672)
#define OFF_UFBF  ((size_t)3229696)
#define OFF_UMMFBF ((size_t)3870720)
#define OFF_WP    ((size_t)5324800)   // 573,440 shorts = 286,720 floats
#define OFF_E     ((size_t)5611520)
#define OFF_EBF   ((size_t)5677056)   // 65,536 shorts = 32,768 floats
#define OFF_UST   ((size_t)5709824)
#define OFF_VB    ((size_t)5718016)
#define OFF_S2    ((size_t)5718080)
#define OFF_T     ((size_t)5718208)
#define OFF_UF    ((size_t)5723328)
// end = 7,003,328 floats = 28.0 MB

// ---------------- prep: x -> bf16 padded [128][260][320] ----------------
__global__ __launch_bounds__(320) void prep_x_kernel(const float* __restrict__ x, short* __restrict__ xp)
{
    const int row = blockIdx.x;            // 0..259
    const int b   = blockIdx.y;            // 0..127
    const int c   = threadIdx.x;           // 0..319
    float v = 0.f;
    if (row < L_ && c < C_) v = x[((size_t)b * L_ + row) * C_ + c];
    xp[((size_t)b * LP_ + row) * CP_ + c] = (short)f2bf(v);
}

// ---------------- prep: conv weights -> bf16 [br][k][tap][320] ----------------
__global__ void prep_w_kernel(const float* __restrict__ w2, const float* __restrict__ w3,
                              const float* __restrict__ w4, const float* __restrict__ w5,
                              short* __restrict__ wp)
{
    const int idx = blockIdx.x * 256 + threadIdx.x;
    if (idx >= 128 * 14 * CP_) return;
    int off, wsz; const float* src;
    if (idx < 81920)       { off = idx;          wsz = 2; src = w2; }
    else if (idx < 204800) { off = idx - 81920;  wsz = 3; src = w3; }
    else if (idx < 368640) { off = idx - 204800; wsz = 4; src = w4; }
    else                   { off = idx - 368640; wsz = 5; src = w5; }
    const int k   = off / (wsz * CP_);
    const int r   = off % (wsz * CP_);
    const int tap = r / CP_;
    const int c   = r % CP_;
    float v = 0.f;
    if (c < C_) v = src[((size_t)k * C_ + c) * wsz + tap];
    wp[idx] = (short)f2bf(v);
}

// ---------------- conv implicit-GEMM + fused relu/bias/maxpool ----------------
// grid (nt=2, br=4, b=128), block 512 (8 waves: 4 m-waves x 2 n-waves)
__global__ __launch_bounds__(512) void conv_gemm_kernel(
    const short* __restrict__ xp, const short* __restrict__ wp,
    const float* __restrict__ b2, const float* __restrict__ b3,
    const float* __restrict__ b4, const float* __restrict__ b5,
    float* __restrict__ e)
{
    const int nt = blockIdx.x;
    const int br = blockIdx.y;
    const int b  = blockIdx.z;
    const int wsz  = br + 2;
    const int Pout = 199 - br;          // L - ws + 1
    const int wbase = (br == 0) ? 0 : (br == 1) ? 81920 : (br == 2) ? 204800 : 368640;

    const int tid  = threadIdx.x;
    const int wave = tid >> 6;
    const int lane = tid & 63;
    const int mw   = wave & 3;          // m-wave: rows mw*64..+63
    const int nw   = wave >> 2;         // n-wave: cols nw*32..+31

    __shared__ short lA[256 * 40];      // 20480 B, padded stride 40
    __shared__ short lB[64 * 40];       //  5120 B
    __shared__ float smax[4][64];

    f32x4 acc[4][2];
    #pragma unroll
    for (int mf = 0; mf < 4; ++mf)
        #pragma unroll
        for (int nf = 0; nf < 2; ++nf)
            acc[mf][nf] = (f32x4){0.f, 0.f, 0.f, 0.f};

    const int steps = wsz * 10;
    for (int s = 0; s < steps; ++s) {
        const int tap = s / 10;
        const int cc  = s % 10;
        // stage A: 256 rows x 32 cols bf16 (1024 16B chunks / 512 thr = 2 each)
        #pragma unroll
        for (int i = 0; i < 2; ++i) {
            const int idx  = tid + i * 512;
            const int row  = idx >> 2;
            const int half = idx & 3;
            *(short8*)(lA + row * 40 + half * 8) =
                *(const short8*)(xp + ((size_t)b * LP_ + row + tap) * CP_ + cc * 32 + half * 8);
        }
        // stage B: 64 filters x 32 cols
        if (tid < 256) {
            const int fil  = tid >> 2;
            const int half = tid & 3;
            *(short8*)(lB + fil * 40 + half * 8) =
                *(const short8*)(wp + wbase + (size_t)(nt * 64 + fil) * (wsz * CP_) + tap * CP_ + cc * 32 + half * 8);
        }
        __syncthreads();
        bf16x8 af[4], bfr[2];
        #pragma unroll
        for (int mf = 0; mf < 4; ++mf)
            af[mf] = *(const bf16x8*)(lA + (mw * 64 + mf * 16 + (lane & 15)) * 40 + (lane >> 4) * 8);
        #pragma unroll
        for (int nf = 0; nf < 2; ++nf)
            bfr[nf] = *(const bf16x8*)(lB + (nw * 32 + nf * 16 + (lane & 15)) * 40 + (lane >> 4) * 8);
        #pragma unroll
        for (int mf = 0; mf < 4; ++mf)
            #pragma unroll
            for (int nf = 0; nf < 2; ++nf)
                acc[mf][nf] = MFMA(af[mf], bfr[nf], acc[mf][nf]);
        __syncthreads();
    }

    // epilogue: masked max over p, cross-lane + cross-wave reduce
    float vm0 = -1e30f, vm1 = -1e30f;
    #pragma unroll
    for (int mf = 0; mf < 4; ++mf) {
        const int rowbase = mw * 64 + mf * 16 + (lane >> 4) * 4;
        #pragma unroll
        for (int r = 0; r < 4; ++r) {
            const bool valid = (rowbase + r) < Pout;
            vm0 = fmaxf(vm0, valid ? acc[mf][0][r] : -1e30f);
            vm1 = fmaxf(vm1, valid ? acc[mf][1][r] : -1e30f);
        }
    }
    vm0 = fmaxf(vm0, __shfl_xor(vm0, 16)); vm0 = fmaxf(vm0, __shfl_xor(vm0, 32));
    vm1 = fmaxf(vm1, __shfl_xor(vm1, 16)); vm1 = fmaxf(vm1, __shfl_xor(vm1, 32));
    if (lane < 16) {
        smax[mw][nw * 32 + lane]      = vm0;
        smax[mw][nw * 32 + 16 + lane] = vm1;
    }
    __syncthreads();
    if (tid < 64) {
        const float m = fmaxf(fmaxf(smax[0][tid], smax[1][tid]), fmaxf(smax[2][tid], smax[3][tid]));
        const int k = nt * 64 + tid;
        const float* bp = (br == 0) ? b2 : (br == 1) ? b3 : (br == 2) ? b4 : b5;
        e[(size_t)b * D_ + k * 4 + br] = fmaxf(bp[k] + m, 0.f);
    }
}

// ---------------- prep: fp32 matrix -> bf16 padded [128][Kpad] ----------------
__global__ void prep_u_kernel(const float* __restrict__ src, int srcld,
                              short* __restrict__ dst, int ncols, int Kpad)
{
    const int idx = blockIdx.x * 256 + threadIdx.x;
    if (idx >= B_ * Kpad) return;
    const int b = idx / Kpad;
    const int c = idx % Kpad;
    float v = (c < ncols) ? src[(size_t)b * srcld + c] : 0.f;
    dst[idx] = (short)f2bf(v);
}

// ---------------- MFMA GEMM: partial[z][128][Npad] = A(bf16) @ W(fp32)^T ------
// grid (ceil(N/64), z), block 512 (8 waves: 4 m x 2 n, wave tile 32x32)
__global__ __launch_bounds__(512) void mfma_gemm_kernel(
    const short* __restrict__ Abf, int Kpad,
    const float* __restrict__ W, int K, int N,
    int steps_per_z, float* __restrict__ partial, int Npad)
{
    const int n0 = blockIdx.x * 64;
    const int steps_total = Kpad >> 5;
    const int sbeg = blockIdx.y * steps_per_z;
    const int send = min(sbeg + steps_per_z, steps_total);

    const int tid  = threadIdx.x;
    const int wave = tid >> 6;
    const int lane = tid & 63;
    const int mw   = wave & 3;
    const int nw   = wave >> 2;

    __shared__ short lA[128 * 40];
    __shared__ short lB[64 * 40];

    f32x4 acc[2][2];
    #pragma unroll
    for (int mf = 0; mf < 2; ++mf)
        #pragma unroll
        for (int nf = 0; nf < 2; ++nf)
            acc[mf][nf] = (f32x4){0.f, 0.f, 0.f, 0.f};

    for (int s = sbeg; s < send; ++s) {
        const int kbase = s * 32;
        // stage A: 128 rows x 32 cols bf16 (512 chunks / 512 thr)
        {
            const int row  = tid >> 2;
            const int half = tid & 3;
            *(short8*)(lA + row * 40 + half * 8) =
                *(const short8*)(Abf + (size_t)row * Kpad + kbase + half * 8);
        }
        // stage B: 64 rows x 32 cols, fp32 -> bf16 (512 float4 / 512 thr)
        {
            const int fil = tid >> 3;
            const int q   = tid & 7;
            const int k   = kbase + q * 4;
            float4 wv = make_float4(0.f, 0.f, 0.f, 0.f);
            if ((n0 + fil) < N && k < K)
                wv = *(const float4*)(W + (size_t)(n0 + fil) * K + k);
            short4v sv;
            sv.x = (short)f2bf(wv.x); sv.y = (short)f2bf(wv.y);
            sv.z = (short)f2bf(wv.z); sv.w = (short)f2bf(wv.w);
            *(short4v*)(lB + fil * 40 + q * 4) = sv;
        }
        __syncthreads();
        bf16x8 af[2], bfr[2];
        #pragma unroll
        for (int mf = 0; mf < 2; ++mf)
            af[mf] = *(const bf16x8*)(lA + (mw * 32 + mf * 16 + (lane & 15)) * 40 + (lane >> 4) * 8);
        #pragma unroll
        for (int nf = 0; nf < 2; ++nf)
            bfr[nf] = *(const bf16x8*)(lB + (nw * 32 + nf * 16 + (lane & 15)) * 40 + (lane >> 4) * 8);
        #pragma unroll
        for (int mf = 0; mf < 2; ++mf)
            #pragma unroll
            for (int nf = 0; nf < 2; ++nf)
                acc[mf][nf] = MFMA(af[mf], bfr[nf], acc[mf][nf]);
        __syncthreads();
    }

    // write partial
    #pragma unroll
    for (int mf = 0; mf < 2; ++mf)
        #pragma unroll
        for (int nf = 0; nf < 2; ++nf)
            #pragma unroll
            for (int r = 0; r < 4; ++r) {
                const int row = mw * 32 + mf * 16 + (lane >> 4) * 4 + r;
                const int col = nw * 32 + nf * 16 + (lane & 15);
                partial[((size_t)blockIdx.y * B_ + row) * Npad + n0 + col] = acc[mf][nf][r];
            }
}

// ---------------- old fp32 GEMM (kept for tiny ust) ----------------
__global__ __launch_bounds__(256) void gemm_bt_kernel(
    const float* __restrict__ in, int ldin,
    const float* __restrict__ W, int kdim, int N, int jper,
    float* __restrict__ partial)
{
    const int n  = blockIdx.x * 256 + threadIdx.x;
    const int b0 = blockIdx.y * 32;
    const int jlo = blockIdx.z * jper;
    const int jhi = min(jlo + jper, kdim);
    if (n >= N) return;
    float acc[32];
    #pragma unroll
    for (int i = 0; i < 32; ++i) acc[i] = 0.f;
    const float* wr = W + (size_t)n * kdim;
    for (int j = jlo; j < jhi; j += 4) {
        const float4 w4 = *(const float4*)(wr + j);
        #pragma unroll
        for (int bi = 0; bi < 32; ++bi) {
            const float4 iv = *(const float4*)(in + (size_t)(b0 + bi) * ldin + j);
            acc[bi] += w4.x*iv.x + w4.y*iv.y + w4.z*iv.z + w4.w*iv.w;
        }
    }
    const size_t base = ((size_t)blockIdx.z * B_ + b0) * N + n;
    #pragma unroll
    for (int bi = 0; bi < 32; ++bi)
        partial[base + (size_t)bi * N] = acc[bi];
}

// sum partials + bias (+tanh) -> out[b*ldo + ooff + n]; partial stride Npad
__global__ void reduce_kernel(const float* __restrict__ partial, const float* __restrict__ bias,
                              float* __restrict__ out, int N, int ldo, int ooff, int js, int act, int Npad)
{
    const int idx = blockIdx.x * 256 + threadIdx.x;
    if (idx >= B_ * N) return;
    const int n = idx % N;
    const int b = idx / N;
    float s = bias[n];
    for (int k = 0; k < js; ++k) s += partial[((size_t)k * B_ + b) * Npad + n];
    if (act) s = tanhf(s);
    out[(size_t)b * ldo + ooff + n] = s;
}

// ---------------- tiny precompute: vA,vB,c,s2 ----------------
__global__ void prep_kernel(const float* __restrict__ mlp_w1, const float* __restrict__ mlp_b1,
                            const float* __restrict__ mlp_w2, const float* __restrict__ mlp_b2,
                            const float* __restrict__ ust,
                            float* __restrict__ vB, float* __restrict__ s2)
{
    __shared__ float vA[64];
    __shared__ float csh;
    const int tid = threadIdx.x;   // 128 threads
    if (tid < 64) {
        float a = 0.f;
        for (int f = 0; f < 64; ++f) a += mlp_w2[f] * mlp_w1[f * 128 + tid];
        vA[tid] = a;
    } else {
        const int g = tid - 64;
        float bsum = 0.f;
        for (int f = 0; f < 64; ++f) bsum += mlp_w2[f] * mlp_w1[f * 128 + 64 + g];
        vB[g] = bsum;
    }
    if (tid == 0) {
        float c = mlp_b2[0];
        for (int f = 0; f < 64; ++f) c += mlp_b1[f] * mlp_w2[f];
        csh = c;
    }
    __syncthreads();
    float s = csh;
    const float* ub = ust + (size_t)tid * F_;
    for (int g = 0; g < 64; ++g) s += ub[g] * vA[g];
    s2[tid] = s;
}

__global__ void ta_kernel(const float* __restrict__ emb, const float* __restrict__ vB,
                          float* __restrict__ t)
{
    __shared__ float v[64];
    if (threadIdx.x < 64) v[threadIdx.x] = vB[threadIdx.x];
    __syncthreads();
    const int a = blockIdx.x * 256 + threadIdx.x;
    if (a < A_) {
        float acc = 0.f;
        #pragma unroll
        for (int g = 0; g < 64; ++g) acc += v[g] * emb[(size_t)g * A_ + a];
        t[a] = acc;
    }
}

__global__ void um_kernel(const float* __restrict__ ust, const float* __restrict__ emb,
                          const float* __restrict__ s2, const float* __restrict__ t,
                          float* __restrict__ um)
{
    const int b = blockIdx.y;
    __shared__ float us[64];
    if (threadIdx.x < 64) us[threadIdx.x] = ust[(size_t)b * F_ + threadIdx.x];
    __syncthreads();
    const int a = blockIdx.x * 256 + threadIdx.x;
    if (a < A_) {
        float acc = 0.f;
        #pragma unroll
        for (int g = 0; g < 64; ++g) acc += us[g] * emb[(size_t)g * A_ + a];
        um[(size_t)b * (2*A_) + a] = acc;
        um[(size_t)b * (2*A_) + A_ + a] = tanhf(s2[b] + t[a]);
    }
}

// ---------------- launch ----------------
extern "C" void kernel_launch(void* const* d_in, const int* in_sizes, int n_in,
                              void* d_out, int out_size, void* d_ws, size_t ws_size,
                              hipStream_t stream)
{
    const float* x       = (const float*)d_in[0];
    const float* conv_w2 = (const float*)d_in[1];
    const float* conv_b2 = (const float*)d_in[2];
    const float* conv_w3 = (const float*)d_in[3];
    const float* conv_b3 = (const float*)d_in[4];
    const float* conv_w4 = (const float*)d_in[5];
    const float* conv_b4 = (const float*)d_in[6];
    const float* conv_w5 = (const float*)d_in[7];
    const float* conv_b5 = (const float*)d_in[8];
    const float* sc_fcl_w = (const float*)d_in[9];
    const float* sc_fcl_b = (const float*)d_in[10];
    const float* fic_fc_w = (const float*)d_in[11];
    const float* fic_fc_b = (const float*)d_in[12];
    const float* emb      = (const float*)d_in[13];
    const float* mlp_w1   = (const float*)d_in[14];
    const float* mlp_b1   = (const float*)d_in[15];
    const float* mlp_w2   = (const float*)d_in[16];
    const float* mlp_b2   = (const float*)d_in[17];
    const float* fic_fcl_w = (const float*)d_in[18];
    const float* fic_fcl_b = (const float*)d_in[19];
    const float* fusion_w  = (const float*)d_in[20];
    const float* fusion_b  = (const float*)d_in[21];
    const float* task_w    = (const float*)d_in[22];
    const float* task_b    = (const float*)d_in[23];

    float* ws = (float*)d_ws;
    short* xp     = (short*)(ws + OFF_XP);
    float* part   = ws + OFF_PART;
    float* um     = ws + OFF_UM;
    short* umbf   = (short*)(ws + OFF_UMBF);
    float* ummf   = ws + OFF_UMMF;
    short* ufbf   = (short*)(ws + OFF_UFBF);
    short* ummfbf = (short*)(ws + OFF_UMMFBF);
    short* wp     = (short*)(ws + OFF_WP);
    float* e      = ws + OFF_E;
    short* ebf    = (short*)(ws + OFF_EBF);
    float* ust    = ws + OFF_UST;
    float* vB     = ws + OFF_VB;
    float* s2     = ws + OFF_S2;
    float* t      = ws + OFF_T;
    float* uf     = ws + OFF_UF;
    float* out    = (float*)d_out;

    // 1. preps for conv
    prep_x_kernel<<<dim3(LP_, B_), CP_, 0, stream>>>(x, xp);
    prep_w_kernel<<<(128*14*CP_ + 255)/256, 256, 0, stream>>>(conv_w2, conv_w3, conv_w4, conv_w5, wp);

    // 2. conv implicit-GEMM + fused pool -> e (fp32)
    conv_gemm_kernel<<<dim3(2, 4, B_), 512, 0, stream>>>(xp, wp, conv_b2, conv_b3, conv_b4, conv_b5, e);

    // 3. e -> bf16
    prep_u_kernel<<<(B_*D_ + 255)/256, 256, 0, stream>>>(e, D_, ebf, D_, D_);

    // 4. u_sc = e @ sc_fcl_w^T + b -> uf[:, :A]
    mfma_gemm_kernel<<<dim3(79, 1), 512, 0, stream>>>(ebf, D_, sc_fcl_w, D_, A_, 16, part, NPAD_);
    reduce_kernel<<<(B_*A_ + 255)/256, 256, 0, stream>>>(part, sc_fcl_b, uf, A_, 2*A_, 0, 1, 0, NPAD_);

    // 5. ust = e @ fic_fc_w^T + b (tiny fp32 path)
    gemm_bt_kernel<<<dim3(1, 4, 1), 256, 0, stream>>>(e, D_, fic_fc_w, D_, F_, D_, part);
    reduce_kernel<<<(B_*F_ + 255)/256, 256, 0, stream>>>(part, fic_fc_b, ust, F_, F_, 0, 1, 0, F_);

    // 6. mlp collapse precompute + u_mm/u_mlp -> um (fp32, in R0[0..1.28M))
    prep_kernel<<<1, 128, 0, stream>>>(mlp_w1, mlp_b1, mlp_w2, mlp_b2, ust, vB, s2);
    ta_kernel<<<(A_ + 255)/256, 256, 0, stream>>>(emb, vB, t);
    um_kernel<<<dim3((A_ + 255)/256, B_), 256, 0, stream>>>(ust, emb, s2, t, um);

    // 7. um -> bf16 padded
    prep_u_kernel<<<(B_*10016 + 255)/256, 256, 0, stream>>>(um, 2*A_, umbf, 2*A_, 10016);

    // 8. u_fic = tanh(um @ fic_fcl_w^T + b) -> uf[:, A:]
    mfma_gemm_kernel<<<dim3(79, 4), 512, 0, stream>>>(umbf, 10016, fic_fcl_w, 2*A_, A_, 79, part, NPAD_);
    reduce_kernel<<<(B_*A_ + 255)/256, 256, 0, stream>>>(part, fic_fcl_b, uf, A_, 2*A_, A_, 4, 1, NPAD_);

    // 9. uf -> bf16 padded
    prep_u_kernel<<<(B_*10016 + 255)/256, 256, 0, stream>>>(uf, 2*A_, ufbf, 2*A_, 10016);

    // 10. u_mmf = uf @ fusion_w^T + b -> ummf
    mfma_gemm_kernel<<<dim3(79, 4), 512, 0, stream>>>(ufbf, 10016, fusion_w, 2*A_, A_, 79, part, NPAD_);
    reduce_kernel<<<(B_*A_ + 255)/256, 256, 0, stream>>>(part, fusion_b, ummf, A_, A_, 0, 4, 0, NPAD_);

    // 11. ummf -> bf16 padded
    prep_u_kernel<<<(B_*5024 + 255)/256, 256, 0, stream>>>(ummf, A_, ummfbf, A_, 5024);

    // 12. task = ummf @ task_w^T + b -> out
    mfma_gemm_kernel<<<dim3(79, 4), 512, 0, stream>>>(ummfbf, 5024, task_w, A_, A_, 40, part, NPAD_);
    reduce_kernel<<<(B_*A_ + 255)/256, 256, 0, stream>>>(part, task_b, out, A_, A_, 0, 4, 0, NPAD_);
}

// Round 4
// 446.179 us; speedup vs baseline: 8.9082x; 1.4563x over previous
//
#include <hip/hip_runtime.h>
#include <math.h>

#define B_ 128
#define L_ 200
#define C_ 300
#define K_ 128
#define A_ 5000
#define F_ 64
#define D_ 512
#define CP_ 320      // padded C
#define LP_ 260      // padded L rows
#define NPAD_ 5056   // 79*64
#define KP2_ 10048   // 157*64 (padded 2A)
#define KP1_ 5056    // 79*64  (padded A)

typedef __attribute__((ext_vector_type(8))) short bf16x8;
typedef __attribute__((ext_vector_type(8))) short short8;
typedef __attribute__((ext_vector_type(4))) float f32x4;

#define MFMA(a,b,c) __builtin_amdgcn_mfma_f32_16x16x32_bf16(a,b,c,0,0,0)

static __device__ __forceinline__ unsigned short f2bf(float f) {
    unsigned u = __float_as_uint(f);
    unsigned r = (u + 0x7FFFu + ((u >> 16) & 1u)) >> 16;
    return (unsigned short)r;
}

// ---------------- workspace layout (float offsets) ----------------
// A region [0, 5,324,800): xp (conv phase) -> partial (gemm phase, z<=8: 5,177,344)
// B region [5,324,800, 5,967,872): wp(286,720)+e(65,536)+ebf(32,768) -> umbf(643,072) -> ummfbf(323,584)
// C region [5,967,872, 5,981,312): ust, vB, s2, t
// D region [5,981,312, 6,624,384): ufbf (643,072)
// end = 6,624,384 floats = 26.5 MB
#define OFF_XP     ((size_t)0)
#define OFF_PART   ((size_t)0)
#define OFF_WP     ((size_t)5324800)
#define OFF_E      ((size_t)5611520)
#define OFF_EBF    ((size_t)5677056)
#define OFF_UMBF   ((size_t)5324800)
#define OFF_UMMFBF ((size_t)5324800)
#define OFF_UST    ((size_t)5967872)
#define OFF_VB     ((size_t)5976064)
#define OFF_S2     ((size_t)5976128)
#define OFF_T      ((size_t)5976256)
#define OFF_UFBF   ((size_t)5981312)

// ---------------- prep: x -> bf16 padded [128][260][320] ----------------
__global__ __launch_bounds__(320) void prep_x_kernel(const float* __restrict__ x, short* __restrict__ xp)
{
    const int row = blockIdx.x;
    const int b   = blockIdx.y;
    const int c   = threadIdx.x;
    float v = 0.f;
    if (row < L_ && c < C_) v = x[((size_t)b * L_ + row) * C_ + c];
    xp[((size_t)b * LP_ + row) * CP_ + c] = (short)f2bf(v);
}

// ---------------- prep: conv weights -> bf16 [br][k][tap][320] ----------------
__global__ void prep_w_kernel(const float* __restrict__ w2, const float* __restrict__ w3,
                              const float* __restrict__ w4, const float* __restrict__ w5,
                              short* __restrict__ wp)
{
    const int idx = blockIdx.x * 256 + threadIdx.x;
    if (idx >= 128 * 14 * CP_) return;
    int off, wsz; const float* src;
    if (idx < 81920)       { off = idx;          wsz = 2; src = w2; }
    else if (idx < 204800) { off = idx - 81920;  wsz = 3; src = w3; }
    else if (idx < 368640) { off = idx - 204800; wsz = 4; src = w4; }
    else                   { off = idx - 368640; wsz = 5; src = w5; }
    const int k   = off / (wsz * CP_);
    const int r   = off % (wsz * CP_);
    const int tap = r / CP_;
    const int c   = r % CP_;
    float v = 0.f;
    if (c < C_) v = src[((size_t)k * C_ + c) * wsz + tap];
    wp[idx] = (short)f2bf(v);
}

// ---------------- conv implicit-GEMM v2: tap-shift, x staged once ----------------
// grid (b=128, br=4, nt=2), block 512 (8 waves: 4m x 2n)
__global__ __launch_bounds__(512) void conv_gemm2_kernel(
    const short* __restrict__ xp, const short* __restrict__ wp,
    const float* __restrict__ b2, const float* __restrict__ b3,
    const float* __restrict__ b4, const float* __restrict__ b5,
    float* __restrict__ e)
{
    const int b  = blockIdx.x;
    const int br = blockIdx.y;
    const int nt = blockIdx.z;
    const int wsz  = br + 2;
    const int Pout = 199 - br;
    const int wbase = (br == 0) ? 0 : (br == 1) ? 81920 : (br == 2) ? 204800 : 368640;

    const int tid  = threadIdx.x;
    const int wave = tid >> 6;
    const int lane = tid & 63;
    const int mw   = wave & 3;
    const int nw   = wave >> 2;

    __shared__ short lA[260 * 36];      // 18.7 KB, stride 36 shorts
    __shared__ short lB[5 * 64 * 36];   // 23.0 KB
    __shared__ float smax[4][64];

    f32x4 acc[4][2];
    #pragma unroll
    for (int mf = 0; mf < 4; ++mf)
        #pragma unroll
        for (int nf = 0; nf < 2; ++nf)
            acc[mf][nf] = (f32x4){0.f, 0.f, 0.f, 0.f};

    for (int cc = 0; cc < 10; ++cc) {
        // stage A: 260 rows x 32 cols (1040 chunks)
        for (int ch = tid; ch < 1040; ch += 512) {
            const int row = ch >> 2, half = ch & 3;
            *(short8*)(lA + row * 36 + half * 8) =
                *(const short8*)(xp + ((size_t)b * LP_ + row) * CP_ + cc * 32 + half * 8);
        }
        // stage B: ws taps x 64 filters x 32 cols
        for (int ch = tid; ch < wsz * 256; ch += 512) {
            const int tap = ch >> 8;
            const int r2  = ch & 255;
            const int fil = r2 >> 2, half = r2 & 3;
            *(short8*)(lB + (tap * 64 + fil) * 36 + half * 8) =
                *(const short8*)(wp + wbase + (size_t)(nt * 64 + fil) * (wsz * CP_) + tap * CP_ + cc * 32 + half * 8);
        }
        __syncthreads();
        for (int tap = 0; tap < wsz; ++tap) {
            bf16x8 af[4], bfr[2];
            #pragma unroll
            for (int mf = 0; mf < 4; ++mf)
                af[mf] = *(const bf16x8*)(lA + (mw * 64 + mf * 16 + (lane & 15) + tap) * 36 + (lane >> 4) * 8);
            #pragma unroll
            for (int nf = 0; nf < 2; ++nf)
                bfr[nf] = *(const bf16x8*)(lB + (tap * 64 + nw * 32 + nf * 16 + (lane & 15)) * 36 + (lane >> 4) * 8);
            #pragma unroll
            for (int mf = 0; mf < 4; ++mf)
                #pragma unroll
                for (int nf = 0; nf < 2; ++nf)
                    acc[mf][nf] = MFMA(af[mf], bfr[nf], acc[mf][nf]);
        }
        __syncthreads();
    }

    // epilogue: masked max over positions
    float vm0 = -1e30f, vm1 = -1e30f;
    #pragma unroll
    for (int mf = 0; mf < 4; ++mf) {
        const int rowbase = mw * 64 + mf * 16 + (lane >> 4) * 4;
        #pragma unroll
        for (int r = 0; r < 4; ++r) {
            const bool valid = (rowbase + r) < Pout;
            vm0 = fmaxf(vm0, valid ? acc[mf][0][r] : -1e30f);
            vm1 = fmaxf(vm1, valid ? acc[mf][1][r] : -1e30f);
        }
    }
    vm0 = fmaxf(vm0, __shfl_xor(vm0, 16)); vm0 = fmaxf(vm0, __shfl_xor(vm0, 32));
    vm1 = fmaxf(vm1, __shfl_xor(vm1, 16)); vm1 = fmaxf(vm1, __shfl_xor(vm1, 32));
    if (lane < 16) {
        smax[mw][nw * 32 + lane]      = vm0;
        smax[mw][nw * 32 + 16 + lane] = vm1;
    }
    __syncthreads();
    if (tid < 64) {
        const float m = fmaxf(fmaxf(smax[0][tid], smax[1][tid]), fmaxf(smax[2][tid], smax[3][tid]));
        const int k = nt * 64 + tid;
        const float* bp = (br == 0) ? b2 : (br == 1) ? b3 : (br == 2) ? b4 : b5;
        e[(size_t)b * D_ + k * 4 + br] = fmaxf(bp[k] + m, 0.f);
    }
}

// ---------------- prep: fp32 matrix -> bf16 padded ----------------
__global__ void prep_u_kernel(const float* __restrict__ src, int srcld,
                              short* __restrict__ dst, int ncols, int Kpad)
{
    const int idx = blockIdx.x * 256 + threadIdx.x;
    if (idx >= B_ * Kpad) return;
    const int b = idx / Kpad;
    const int c = idx % Kpad;
    float v = (c < ncols) ? src[(size_t)b * srcld + c] : 0.f;
    dst[idx] = (short)f2bf(v);
}

// ---------------- big MFMA GEMM v2: K-phase 64, reg prefetch ----------------
// grid (79, z), block 512 (8 waves: 4m x 2n), tile M=128 N=64
__global__ __launch_bounds__(512) void gemm2_kernel(
    const short* __restrict__ Abf, int Kpad,
    const float* __restrict__ W, int K, int N,
    int steps_per_z, float* __restrict__ partial)
{
    const int n0 = blockIdx.x * 64;
    const int total = Kpad >> 6;
    const int sbeg = blockIdx.y * steps_per_z;
    const int send = min(sbeg + steps_per_z, total);

    const int tid  = threadIdx.x;
    const int wave = tid >> 6;
    const int lane = tid & 63;
    const int mw   = wave & 3;
    const int nw   = wave >> 2;

    __shared__ short lA[128 * 68];
    __shared__ short lB[64 * 68];

    // staging coords
    const int arow = tid >> 2, ac0 = (tid & 3) * 16;          // A: 2 short8 per thread
    const int fil  = tid >> 3, wc0 = (tid & 7) * 8;           // W: 2 float4 per thread

    f32x4 acc[2][2];
    #pragma unroll
    for (int mf = 0; mf < 2; ++mf)
        #pragma unroll
        for (int nf = 0; nf < 2; ++nf)
            acc[mf][nf] = (f32x4){0.f, 0.f, 0.f, 0.f};

    short8 ra0, ra1;
    float4 rw0, rw1;
    const bool wrow_ok = (n0 + fil) < N;

    // prologue: load phase sbeg
    {
        const int kb = sbeg * 64;
        ra0 = *(const short8*)(Abf + (size_t)arow * Kpad + kb + ac0);
        ra1 = *(const short8*)(Abf + (size_t)arow * Kpad + kb + ac0 + 8);
        rw0 = make_float4(0.f,0.f,0.f,0.f); rw1 = rw0;
        if (wrow_ok && (kb + wc0) < K)     rw0 = *(const float4*)(W + (size_t)(n0 + fil) * K + kb + wc0);
        if (wrow_ok && (kb + wc0 + 4) < K) rw1 = *(const float4*)(W + (size_t)(n0 + fil) * K + kb + wc0 + 4);
    }

    for (int s = sbeg; s < send; ++s) {
        __syncthreads();   // prior phase's LDS reads complete
        // write staged regs -> LDS
        *(short8*)(lA + arow * 68 + ac0)     = ra0;
        *(short8*)(lA + arow * 68 + ac0 + 8) = ra1;
        {
            short8 wb;
            wb[0]=(short)f2bf(rw0.x); wb[1]=(short)f2bf(rw0.y); wb[2]=(short)f2bf(rw0.z); wb[3]=(short)f2bf(rw0.w);
            wb[4]=(short)f2bf(rw1.x); wb[5]=(short)f2bf(rw1.y); wb[6]=(short)f2bf(rw1.z); wb[7]=(short)f2bf(rw1.w);
            *(short8*)(lB + fil * 68 + wc0) = wb;
        }
        // issue next phase's loads
        if (s + 1 < send) {
            const int kb = (s + 1) * 64;
            ra0 = *(const short8*)(Abf + (size_t)arow * Kpad + kb + ac0);
            ra1 = *(const short8*)(Abf + (size_t)arow * Kpad + kb + ac0 + 8);
            float4 t0 = make_float4(0.f,0.f,0.f,0.f), t1 = t0;
            if (wrow_ok && (kb + wc0) < K)     t0 = *(const float4*)(W + (size_t)(n0 + fil) * K + kb + wc0);
            if (wrow_ok && (kb + wc0 + 4) < K) t1 = *(const float4*)(W + (size_t)(n0 + fil) * K + kb + wc0 + 4);
            rw0 = t0; rw1 = t1;
        }
        __syncthreads();
        #pragma unroll
        for (int ks = 0; ks < 2; ++ks) {
            bf16x8 af[2], bfr[2];
            #pragma unroll
            for (int mf = 0; mf < 2; ++mf)
                af[mf] = *(const bf16x8*)(lA + (mw * 32 + mf * 16 + (lane & 15)) * 68 + ks * 32 + (lane >> 4) * 8);
            #pragma unroll
            for (int nf = 0; nf < 2; ++nf)
                bfr[nf] = *(const bf16x8*)(lB + (nw * 32 + nf * 16 + (lane & 15)) * 68 + ks * 32 + (lane >> 4) * 8);
            #pragma unroll
            for (int mf = 0; mf < 2; ++mf)
                #pragma unroll
                for (int nf = 0; nf < 2; ++nf)
                    acc[mf][nf] = MFMA(af[mf], bfr[nf], acc[mf][nf]);
        }
    }

    #pragma unroll
    for (int mf = 0; mf < 2; ++mf)
        #pragma unroll
        for (int nf = 0; nf < 2; ++nf)
            #pragma unroll
            for (int r = 0; r < 4; ++r) {
                const int row = mw * 32 + mf * 16 + (lane >> 4) * 4 + r;
                const int col = nw * 32 + nf * 16 + (lane & 15);
                partial[((size_t)blockIdx.y * B_ + row) * NPAD_ + n0 + col] = acc[mf][nf][r];
            }
}

// ---------------- reduce partials + bias (+tanh) -> bf16 or fp32 ----------------
__global__ void reduce2_kernel(const float* __restrict__ partial, const float* __restrict__ bias,
                               float* __restrict__ outf, short* __restrict__ outb,
                               int N, int ldo, int ooff, int js, int act)
{
    const int idx = blockIdx.x * 256 + threadIdx.x;
    if (idx >= B_ * N) return;
    const int n = idx % N;
    const int b = idx / N;
    float s = bias[n];
    for (int k = 0; k < js; ++k) s += partial[((size_t)k * B_ + b) * NPAD_ + n];
    if (act) s = tanhf(s);
    if (outb) outb[(size_t)b * ldo + ooff + n] = (short)f2bf(s);
    else      outf[(size_t)b * ldo + ooff + n] = s;
}

// ---------------- small fp32 GEMM (ust) ----------------
__global__ __launch_bounds__(256) void gemm_bt_kernel(
    const float* __restrict__ in, int ldin,
    const float* __restrict__ W, int kdim, int N, int jper,
    float* __restrict__ partial)
{
    const int n  = blockIdx.x * 256 + threadIdx.x;
    const int b0 = blockIdx.y * 32;
    const int jlo = blockIdx.z * jper;
    const int jhi = min(jlo + jper, kdim);
    if (n >= N) return;
    float acc[32];
    #pragma unroll
    for (int i = 0; i < 32; ++i) acc[i] = 0.f;
    const float* wr = W + (size_t)n * kdim;
    for (int j = jlo; j < jhi; j += 4) {
        const float4 w4 = *(const float4*)(wr + j);
        #pragma unroll
        for (int bi = 0; bi < 32; ++bi) {
            const float4 iv = *(const float4*)(in + (size_t)(b0 + bi) * ldin + j);
            acc[bi] += w4.x*iv.x + w4.y*iv.y + w4.z*iv.z + w4.w*iv.w;
        }
    }
    const size_t base = ((size_t)blockIdx.z * B_ + b0) * N + n;
    #pragma unroll
    for (int bi = 0; bi < 32; ++bi)
        partial[base + (size_t)bi * N] = acc[bi];
}

__global__ void reduce_kernel(const float* __restrict__ partial, const float* __restrict__ bias,
                              float* __restrict__ out, int N, int ldo, int ooff, int js, int act, int Npad)
{
    const int idx = blockIdx.x * 256 + threadIdx.x;
    if (idx >= B_ * N) return;
    const int n = idx % N;
    const int b = idx / N;
    float s = bias[n];
    for (int k = 0; k < js; ++k) s += partial[((size_t)k * B_ + b) * Npad + n];
    if (act) s = tanhf(s);
    out[(size_t)b * ldo + ooff + n] = s;
}

// ---------------- tiny precompute: vA,vB,c,s2 ----------------
__global__ void prep_kernel(const float* __restrict__ mlp_w1, const float* __restrict__ mlp_b1,
                            const float* __restrict__ mlp_w2, const float* __restrict__ mlp_b2,
                            const float* __restrict__ ust,
                            float* __restrict__ vB, float* __restrict__ s2)
{
    __shared__ float vA[64];
    __shared__ float csh;
    const int tid = threadIdx.x;   // 128 threads
    if (tid < 64) {
        float a = 0.f;
        for (int f = 0; f < 64; ++f) a += mlp_w2[f] * mlp_w1[f * 128 + tid];
        vA[tid] = a;
    } else {
        const int g = tid - 64;
        float bsum = 0.f;
        for (int f = 0; f < 64; ++f) bsum += mlp_w2[f] * mlp_w1[f * 128 + 64 + g];
        vB[g] = bsum;
    }
    if (tid == 0) {
        float c = mlp_b2[0];
        for (int f = 0; f < 64; ++f) c += mlp_b1[f] * mlp_w2[f];
        csh = c;
    }
    __syncthreads();
    float s = csh;
    const float* ub = ust + (size_t)tid * F_;
    for (int g = 0; g < 64; ++g) s += ub[g] * vA[g];
    s2[tid] = s;
}

__global__ void ta_kernel(const float* __restrict__ emb, const float* __restrict__ vB,
                          float* __restrict__ t)
{
    __shared__ float v[64];
    if (threadIdx.x < 64) v[threadIdx.x] = vB[threadIdx.x];
    __syncthreads();
    const int a = blockIdx.x * 256 + threadIdx.x;
    if (a < A_) {
        float acc = 0.f;
        #pragma unroll
        for (int g = 0; g < 64; ++g) acc += v[g] * emb[(size_t)g * A_ + a];
        t[a] = acc;
    }
}

// um bf16: col a = ust[b]@emb[:,a]; col 5000+a = tanh(s2[b]+t[a]); pad cols zeroed
__global__ void um2_kernel(const float* __restrict__ ust, const float* __restrict__ emb,
                           const float* __restrict__ s2, const float* __restrict__ t,
                           short* __restrict__ umb)
{
    const int b = blockIdx.y;
    __shared__ float us[64];
    if (threadIdx.x < 64) us[threadIdx.x] = ust[(size_t)b * F_ + threadIdx.x];
    __syncthreads();
    const int a = blockIdx.x * 256 + threadIdx.x;
    if (a < A_) {
        float acc = 0.f;
        #pragma unroll
        for (int g = 0; g < 64; ++g) acc += us[g] * emb[(size_t)g * A_ + a];
        umb[(size_t)b * KP2_ + a] = (short)f2bf(acc);
        umb[(size_t)b * KP2_ + A_ + a] = (short)f2bf(tanhf(s2[b] + t[a]));
    } else if (a < A_ + 48) {
        umb[(size_t)b * KP2_ + A_ + a] = 0;   // cols 10000..10047
    }
}

// zero pad columns of a bf16 buffer
__global__ void pad_kernel(short* __restrict__ buf, int ld, int c0, int n)
{
    const int b = blockIdx.x;
    for (int c = threadIdx.x; c < n; c += 64)
        buf[(size_t)b * ld + c0 + c] = 0;
}

// ---------------- launch ----------------
extern "C" void kernel_launch(void* const* d_in, const int* in_sizes, int n_in,
                              void* d_out, int out_size, void* d_ws, size_t ws_size,
                              hipStream_t stream)
{
    const float* x       = (const float*)d_in[0];
    const float* conv_w2 = (const float*)d_in[1];
    const float* conv_b2 = (const float*)d_in[2];
    const float* conv_w3 = (const float*)d_in[3];
    const float* conv_b3 = (const float*)d_in[4];
    const float* conv_w4 = (const float*)d_in[5];
    const float* conv_b4 = (const float*)d_in[6];
    const float* conv_w5 = (const float*)d_in[7];
    const float* conv_b5 = (const float*)d_in[8];
    const float* sc_fcl_w = (const float*)d_in[9];
    const float* sc_fcl_b = (const float*)d_in[10];
    const float* fic_fc_w = (const float*)d_in[11];
    const float* fic_fc_b = (const float*)d_in[12];
    const float* emb      = (const float*)d_in[13];
    const float* mlp_w1   = (const float*)d_in[14];
    const float* mlp_b1   = (const float*)d_in[15];
    const float* mlp_w2   = (const float*)d_in[16];
    const float* mlp_b2   = (const float*)d_in[17];
    const float* fic_fcl_w = (const float*)d_in[18];
    const float* fic_fcl_b = (const float*)d_in[19];
    const float* fusion_w  = (const float*)d_in[20];
    const float* fusion_b  = (const float*)d_in[21];
    const float* task_w    = (const float*)d_in[22];
    const float* task_b    = (const float*)d_in[23];

    float* ws = (float*)d_ws;
    short* xp     = (short*)(ws + OFF_XP);
    float* part   = ws + OFF_PART;
    short* wp     = (short*)(ws + OFF_WP);
    float* e      = ws + OFF_E;
    short* ebf    = (short*)(ws + OFF_EBF);
    short* umbf   = (short*)(ws + OFF_UMBF);
    short* ummfbf = (short*)(ws + OFF_UMMFBF);
    float* ust    = ws + OFF_UST;
    float* vB     = ws + OFF_VB;
    float* s2     = ws + OFF_S2;
    float* t      = ws + OFF_T;
    short* ufbf   = (short*)(ws + OFF_UFBF);
    float* out    = (float*)d_out;

    // 1-2. preps
    prep_x_kernel<<<dim3(LP_, B_), CP_, 0, stream>>>(x, xp);
    prep_w_kernel<<<(128*14*CP_ + 255)/256, 256, 0, stream>>>(conv_w2, conv_w3, conv_w4, conv_w5, wp);

    // 3. conv v2 -> e (fp32); grid (b, br, nt) keeps same-b blocks on one XCD
    conv_gemm2_kernel<<<dim3(B_, 4, 2), 512, 0, stream>>>(xp, wp, conv_b2, conv_b3, conv_b4, conv_b5, e);

    // 4. e -> bf16
    prep_u_kernel<<<(B_*D_ + 255)/256, 256, 0, stream>>>(e, D_, ebf, D_, D_);

    // 5-6. u_sc -> ufbf cols [0,5000)
    gemm2_kernel<<<dim3(79, 4), 512, 0, stream>>>(ebf, D_, sc_fcl_w, D_, A_, 2, part);
    reduce2_kernel<<<(B_*A_ + 255)/256, 256, 0, stream>>>(part, sc_fcl_b, nullptr, ufbf, A_, KP2_, 0, 4, 0);
    pad_kernel<<<B_, 64, 0, stream>>>(ufbf, KP2_, 2*A_, 48);

    // 7-8. ust (tiny fp32 path)
    gemm_bt_kernel<<<dim3(1, 4, 1), 256, 0, stream>>>(e, D_, fic_fc_w, D_, F_, D_, part);
    reduce_kernel<<<(B_*F_ + 255)/256, 256, 0, stream>>>(part, fic_fc_b, ust, F_, F_, 0, 1, 0, F_);

    // 9-11. mlp collapse + um (bf16 direct)
    prep_kernel<<<1, 128, 0, stream>>>(mlp_w1, mlp_b1, mlp_w2, mlp_b2, ust, vB, s2);
    ta_kernel<<<(A_ + 255)/256, 256, 0, stream>>>(emb, vB, t);
    um2_kernel<<<dim3(20, B_), 256, 0, stream>>>(ust, emb, s2, t, umbf);

    // 12-13. u_fic = tanh(um @ fic_fcl_w^T + b) -> ufbf cols [5000,10000)
    gemm2_kernel<<<dim3(79, 8), 512, 0, stream>>>(umbf, KP2_, fic_fcl_w, 2*A_, A_, 20, part);
    reduce2_kernel<<<(B_*A_ + 255)/256, 256, 0, stream>>>(part, fic_fcl_b, nullptr, ufbf, A_, KP2_, A_, 8, 1);

    // 14-15. u_mmf = uf @ fusion_w^T + b -> ummfbf
    gemm2_kernel<<<dim3(79, 8), 512, 0, stream>>>(ufbf, KP2_, fusion_w, 2*A_, A_, 20, part);
    reduce2_kernel<<<(B_*A_ + 255)/256, 256, 0, stream>>>(part, fusion_b, nullptr, ummfbf, A_, KP1_, 0, 8, 0);
    pad_kernel<<<B_, 64, 0, stream>>>(ummfbf, KP1_, A_, 56);

    // 16-17. task = ummf @ task_w^T + b -> out (fp32)
    gemm2_kernel<<<dim3(79, 8), 512, 0, stream>>>(ummfbf, KP1_, task_w, A_, A_, 10, part);
    reduce2_kernel<<<(B_*A_ + 255)/256, 256, 0, stream>>>(part, task_b, out, nullptr, A_, A_, 0, 8, 0);
}

// Round 5
// 328.259 us; speedup vs baseline: 12.1083x; 1.3592x over previous
//
#include <hip/hip_runtime.h>
#include <math.h>

#define B_ 128
#define L_ 200
#define C_ 300
#define K_ 128
#define A_ 5000
#define F_ 64
#define D_ 512
#define CP_ 320      // padded C
#define LP_ 260      // padded L rows
#define NPAD_ 5056   // 79*64
#define KP2_ 10048   // 157*64 (padded 2A)
#define KP1_ 5056    // 79*64  (padded A)

typedef __attribute__((ext_vector_type(8))) short bf16x8;
typedef __attribute__((ext_vector_type(8))) short short8;
typedef __attribute__((ext_vector_type(4))) float f32x4;

#define MFMA(a,b,c) __builtin_amdgcn_mfma_f32_16x16x32_bf16(a,b,c,0,0,0)

static __device__ __forceinline__ unsigned short f2bf(float f) {
    unsigned u = __float_as_uint(f);
    unsigned r = (u + 0x7FFFu + ((u >> 16) & 1u)) >> 16;
    return (unsigned short)r;
}

// ---------------- workspace layout (float offsets) ----------------
// A region [0, 5,324,800): xp (conv phase) -> partial (gemm phase, z<=8: 5,177,344)
// B region [5,324,800, 5,967,872): wp(286,720)+e(65,536)+ebf(32,768) -> umbf(643,072) -> ummfbf(323,584)
// C region [5,967,872, 5,981,312): ust, vB, s2, t
// D region [5,981,312, 6,624,384): ufbf (643,072)
#define OFF_XP     ((size_t)0)
#define OFF_PART   ((size_t)0)
#define OFF_WP     ((size_t)5324800)
#define OFF_E      ((size_t)5611520)
#define OFF_EBF    ((size_t)5677056)
#define OFF_UMBF   ((size_t)5324800)
#define OFF_UMMFBF ((size_t)5324800)
#define OFF_UST    ((size_t)5967872)
#define OFF_VB     ((size_t)5976064)
#define OFF_S2     ((size_t)5976128)
#define OFF_T      ((size_t)5976256)
#define OFF_UFBF   ((size_t)5981312)

// ---------------- prep: x -> bf16 padded [128][260][320] ----------------
__global__ __launch_bounds__(320) void prep_x_kernel(const float* __restrict__ x, short* __restrict__ xp)
{
    const int row = blockIdx.x;
    const int b   = blockIdx.y;
    const int c   = threadIdx.x;
    float v = 0.f;
    if (row < L_ && c < C_) v = x[((size_t)b * L_ + row) * C_ + c];
    xp[((size_t)b * LP_ + row) * CP_ + c] = (short)f2bf(v);
}

// ---------------- prep: conv weights -> bf16 [br][k][tap][320] ----------------
__global__ void prep_w_kernel(const float* __restrict__ w2, const float* __restrict__ w3,
                              const float* __restrict__ w4, const float* __restrict__ w5,
                              short* __restrict__ wp)
{
    const int idx = blockIdx.x * 256 + threadIdx.x;
    if (idx >= 128 * 14 * CP_) return;
    int off, wsz; const float* src;
    if (idx < 81920)       { off = idx;          wsz = 2; src = w2; }
    else if (idx < 204800) { off = idx - 81920;  wsz = 3; src = w3; }
    else if (idx < 368640) { off = idx - 204800; wsz = 4; src = w4; }
    else                   { off = idx - 368640; wsz = 5; src = w5; }
    const int k   = off / (wsz * CP_);
    const int r   = off % (wsz * CP_);
    const int tap = r / CP_;
    const int c   = r % CP_;
    float v = 0.f;
    if (c < C_) v = src[((size_t)k * C_ + c) * wsz + tap];
    wp[idx] = (short)f2bf(v);
}

// ---------------- conv implicit-GEMM v2: tap-shift, x staged once ----------------
// grid (b=128, br=4, nt=2), block 512 (8 waves: 4m x 2n)
__global__ __launch_bounds__(512) void conv_gemm2_kernel(
    const short* __restrict__ xp, const short* __restrict__ wp,
    const float* __restrict__ b2, const float* __restrict__ b3,
    const float* __restrict__ b4, const float* __restrict__ b5,
    float* __restrict__ e)
{
    const int b  = blockIdx.x;
    const int br = blockIdx.y;
    const int nt = blockIdx.z;
    const int wsz  = br + 2;
    const int Pout = 199 - br;
    const int wbase = (br == 0) ? 0 : (br == 1) ? 81920 : (br == 2) ? 204800 : 368640;

    const int tid  = threadIdx.x;
    const int wave = tid >> 6;
    const int lane = tid & 63;
    const int mw   = wave & 3;
    const int nw   = wave >> 2;

    __shared__ short lA[260 * 36];      // 18.7 KB, stride 36 shorts
    __shared__ short lB[5 * 64 * 36];   // 23.0 KB
    __shared__ float smax[4][64];

    f32x4 acc[4][2];
    #pragma unroll
    for (int mf = 0; mf < 4; ++mf)
        #pragma unroll
        for (int nf = 0; nf < 2; ++nf)
            acc[mf][nf] = (f32x4){0.f, 0.f, 0.f, 0.f};

    for (int cc = 0; cc < 10; ++cc) {
        // stage A: 260 rows x 32 cols (1040 chunks)
        for (int ch = tid; ch < 1040; ch += 512) {
            const int row = ch >> 2, half = ch & 3;
            *(short8*)(lA + row * 36 + half * 8) =
                *(const short8*)(xp + ((size_t)b * LP_ + row) * CP_ + cc * 32 + half * 8);
        }
        // stage B: ws taps x 64 filters x 32 cols
        for (int ch = tid; ch < wsz * 256; ch += 512) {
            const int tap = ch >> 8;
            const int r2  = ch & 255;
            const int fil = r2 >> 2, half = r2 & 3;
            *(short8*)(lB + (tap * 64 + fil) * 36 + half * 8) =
                *(const short8*)(wp + wbase + (size_t)(nt * 64 + fil) * (wsz * CP_) + tap * CP_ + cc * 32 + half * 8);
        }
        __syncthreads();
        for (int tap = 0; tap < wsz; ++tap) {
            bf16x8 af[4], bfr[2];
            #pragma unroll
            for (int mf = 0; mf < 4; ++mf)
                af[mf] = *(const bf16x8*)(lA + (mw * 64 + mf * 16 + (lane & 15) + tap) * 36 + (lane >> 4) * 8);
            #pragma unroll
            for (int nf = 0; nf < 2; ++nf)
                bfr[nf] = *(const bf16x8*)(lB + (tap * 64 + nw * 32 + nf * 16 + (lane & 15)) * 36 + (lane >> 4) * 8);
            #pragma unroll
            for (int mf = 0; mf < 4; ++mf)
                #pragma unroll
                for (int nf = 0; nf < 2; ++nf)
                    acc[mf][nf] = MFMA(af[mf], bfr[nf], acc[mf][nf]);
        }
        __syncthreads();
    }

    // epilogue: masked max over positions
    float vm0 = -1e30f, vm1 = -1e30f;
    #pragma unroll
    for (int mf = 0; mf < 4; ++mf) {
        const int rowbase = mw * 64 + mf * 16 + (lane >> 4) * 4;
        #pragma unroll
        for (int r = 0; r < 4; ++r) {
            const bool valid = (rowbase + r) < Pout;
            vm0 = fmaxf(vm0, valid ? acc[mf][0][r] : -1e30f);
            vm1 = fmaxf(vm1, valid ? acc[mf][1][r] : -1e30f);
        }
    }
    vm0 = fmaxf(vm0, __shfl_xor(vm0, 16)); vm0 = fmaxf(vm0, __shfl_xor(vm0, 32));
    vm1 = fmaxf(vm1, __shfl_xor(vm1, 16)); vm1 = fmaxf(vm1, __shfl_xor(vm1, 32));
    if (lane < 16) {
        smax[mw][nw * 32 + lane]      = vm0;
        smax[mw][nw * 32 + 16 + lane] = vm1;
    }
    __syncthreads();
    if (tid < 64) {
        const float m = fmaxf(fmaxf(smax[0][tid], smax[1][tid]), fmaxf(smax[2][tid], smax[3][tid]));
        const int k = nt * 64 + tid;
        const float* bp = (br == 0) ? b2 : (br == 1) ? b3 : (br == 2) ? b4 : b5;
        e[(size_t)b * D_ + k * 4 + br] = fmaxf(bp[k] + m, 0.f);
    }
}

// ---------------- prep: fp32 matrix -> bf16 padded ----------------
__global__ void prep_u_kernel(const float* __restrict__ src, int srcld,
                              short* __restrict__ dst, int ncols, int Kpad)
{
    const int idx = blockIdx.x * 256 + threadIdx.x;
    if (idx >= B_ * Kpad) return;
    const int b = idx / Kpad;
    const int c = idx % Kpad;
    float v = (c < ncols) ? src[(size_t)b * srcld + c] : 0.f;
    dst[idx] = (short)f2bf(v);
}

// ---------------- big MFMA GEMM v2: K-phase 64, reg prefetch ----------------
// grid (79, z), block 512 (8 waves: 4m x 2n), tile M=128 N=64
__global__ __launch_bounds__(512) void gemm2_kernel(
    const short* __restrict__ Abf, int Kpad,
    const float* __restrict__ W, int K, int N,
    int steps_per_z, float* __restrict__ partial)
{
    const int n0 = blockIdx.x * 64;
    const int total = Kpad >> 6;
    const int sbeg = blockIdx.y * steps_per_z;
    const int send = min(sbeg + steps_per_z, total);

    const int tid  = threadIdx.x;
    const int wave = tid >> 6;
    const int lane = tid & 63;
    const int mw   = wave & 3;
    const int nw   = wave >> 2;

    __shared__ short lA[128 * 68];
    __shared__ short lB[64 * 68];

    // staging coords
    const int arow = tid >> 2, ac0 = (tid & 3) * 16;          // A: 2 short8 per thread
    const int fil  = tid >> 3, wc0 = (tid & 7) * 8;           // W: 2 float4 per thread

    f32x4 acc[2][2];
    #pragma unroll
    for (int mf = 0; mf < 2; ++mf)
        #pragma unroll
        for (int nf = 0; nf < 2; ++nf)
            acc[mf][nf] = (f32x4){0.f, 0.f, 0.f, 0.f};

    short8 ra0, ra1;
    float4 rw0, rw1;
    const bool wrow_ok = (n0 + fil) < N;

    // prologue: load phase sbeg
    {
        const int kb = sbeg * 64;
        ra0 = *(const short8*)(Abf + (size_t)arow * Kpad + kb + ac0);
        ra1 = *(const short8*)(Abf + (size_t)arow * Kpad + kb + ac0 + 8);
        rw0 = make_float4(0.f,0.f,0.f,0.f); rw1 = rw0;
        if (wrow_ok && (kb + wc0) < K)     rw0 = *(const float4*)(W + (size_t)(n0 + fil) * K + kb + wc0);
        if (wrow_ok && (kb + wc0 + 4) < K) rw1 = *(const float4*)(W + (size_t)(n0 + fil) * K + kb + wc0 + 4);
    }

    for (int s = sbeg; s < send; ++s) {
        __syncthreads();   // prior phase's LDS reads complete
        // write staged regs -> LDS
        *(short8*)(lA + arow * 68 + ac0)     = ra0;
        *(short8*)(lA + arow * 68 + ac0 + 8) = ra1;
        {
            short8 wb;
            wb[0]=(short)f2bf(rw0.x); wb[1]=(short)f2bf(rw0.y); wb[2]=(short)f2bf(rw0.z); wb[3]=(short)f2bf(rw0.w);
            wb[4]=(short)f2bf(rw1.x); wb[5]=(short)f2bf(rw1.y); wb[6]=(short)f2bf(rw1.z); wb[7]=(short)f2bf(rw1.w);
            *(short8*)(lB + fil * 68 + wc0) = wb;
        }
        // issue next phase's loads
        if (s + 1 < send) {
            const int kb = (s + 1) * 64;
            ra0 = *(const short8*)(Abf + (size_t)arow * Kpad + kb + ac0);
            ra1 = *(const short8*)(Abf + (size_t)arow * Kpad + kb + ac0 + 8);
            float4 t0 = make_float4(0.f,0.f,0.f,0.f), t1 = t0;
            if (wrow_ok && (kb + wc0) < K)     t0 = *(const float4*)(W + (size_t)(n0 + fil) * K + kb + wc0);
            if (wrow_ok && (kb + wc0 + 4) < K) t1 = *(const float4*)(W + (size_t)(n0 + fil) * K + kb + wc0 + 4);
            rw0 = t0; rw1 = t1;
        }
        __syncthreads();
        #pragma unroll
        for (int ks = 0; ks < 2; ++ks) {
            bf16x8 af[2], bfr[2];
            #pragma unroll
            for (int mf = 0; mf < 2; ++mf)
                af[mf] = *(const bf16x8*)(lA + (mw * 32 + mf * 16 + (lane & 15)) * 68 + ks * 32 + (lane >> 4) * 8);
            #pragma unroll
            for (int nf = 0; nf < 2; ++nf)
                bfr[nf] = *(const bf16x8*)(lB + (nw * 32 + nf * 16 + (lane & 15)) * 68 + ks * 32 + (lane >> 4) * 8);
            #pragma unroll
            for (int mf = 0; mf < 2; ++mf)
                #pragma unroll
                for (int nf = 0; nf < 2; ++nf)
                    acc[mf][nf] = MFMA(af[mf], bfr[nf], acc[mf][nf]);
        }
    }

    #pragma unroll
    for (int mf = 0; mf < 2; ++mf)
        #pragma unroll
        for (int nf = 0; nf < 2; ++nf)
            #pragma unroll
            for (int r = 0; r < 4; ++r) {
                const int row = mw * 32 + mf * 16 + (lane >> 4) * 4 + r;
                const int col = nw * 32 + nf * 16 + (lane & 15);
                partial[((size_t)blockIdx.y * B_ + row) * NPAD_ + n0 + col] = acc[mf][nf][r];
            }
}

// ---------------- reduce partials + bias (+tanh) -> bf16 or fp32 ----------------
__global__ void reduce2_kernel(const float* __restrict__ partial, const float* __restrict__ bias,
                               float* __restrict__ outf, short* __restrict__ outb,
                               int N, int ldo, int ooff, int js, int act)
{
    const int idx = blockIdx.x * 256 + threadIdx.x;
    if (idx >= B_ * N) return;
    const int n = idx % N;
    const int b = idx / N;
    float s = bias[n];
    for (int k = 0; k < js; ++k) s += partial[((size_t)k * B_ + b) * NPAD_ + n];
    if (act) s = tanhf(s);
    if (outb) outb[(size_t)b * ldo + ooff + n] = (short)f2bf(s);
    else      outf[(size_t)b * ldo + ooff + n] = s;
}

// ---------------- ust: (128,64) = e(128,512) @ fic_fc_w(64,512)^T + b --------
// grid 128 blocks x 256 thr; 4 lanes cooperate per output column
__global__ __launch_bounds__(256) void ust_kernel(
    const float* __restrict__ e, const float* __restrict__ W,
    const float* __restrict__ bias, float* __restrict__ ust)
{
    const int b = blockIdx.x;
    const int f = threadIdx.x >> 2;     // 0..63
    const int q = threadIdx.x & 3;      // 0..3
    const float* er = e + (size_t)b * D_ + q * 128;
    const float* wr = W + (size_t)f * D_ + q * 128;
    float acc = 0.f;
    #pragma unroll
    for (int j = 0; j < 128; j += 4) {
        const float4 ev = *(const float4*)(er + j);
        const float4 wv = *(const float4*)(wr + j);
        acc += ev.x*wv.x + ev.y*wv.y + ev.z*wv.z + ev.w*wv.w;
    }
    acc += __shfl_xor(acc, 1);
    acc += __shfl_xor(acc, 2);
    if (q == 0) ust[(size_t)b * F_ + f] = acc + bias[f];
}

// ---------------- tiny precompute: vA,vB,c,s2 ----------------
__global__ void prep_kernel(const float* __restrict__ mlp_w1, const float* __restrict__ mlp_b1,
                            const float* __restrict__ mlp_w2, const float* __restrict__ mlp_b2,
                            const float* __restrict__ ust,
                            float* __restrict__ vB, float* __restrict__ s2)
{
    __shared__ float vA[64];
    __shared__ float csh;
    const int tid = threadIdx.x;   // 128 threads
    if (tid < 64) {
        float a = 0.f;
        for (int f = 0; f < 64; ++f) a += mlp_w2[f] * mlp_w1[f * 128 + tid];
        vA[tid] = a;
    } else {
        const int g = tid - 64;
        float bsum = 0.f;
        for (int f = 0; f < 64; ++f) bsum += mlp_w2[f] * mlp_w1[f * 128 + 64 + g];
        vB[g] = bsum;
    }
    if (tid == 0) {
        float c = mlp_b2[0];
        for (int f = 0; f < 64; ++f) c += mlp_b1[f] * mlp_w2[f];
        csh = c;
    }
    __syncthreads();
    float s = csh;
    const float* ub = ust + (size_t)tid * F_;
    for (int g = 0; g < 64; ++g) s += ub[g] * vA[g];
    s2[tid] = s;
}

__global__ void ta_kernel(const float* __restrict__ emb, const float* __restrict__ vB,
                          float* __restrict__ t)
{
    __shared__ float v[64];
    if (threadIdx.x < 64) v[threadIdx.x] = vB[threadIdx.x];
    __syncthreads();
    const int a = blockIdx.x * 256 + threadIdx.x;
    if (a < A_) {
        float acc = 0.f;
        #pragma unroll
        for (int g = 0; g < 64; ++g) acc += v[g] * emb[(size_t)g * A_ + a];
        t[a] = acc;
    }
}

// um bf16: col a = ust[b]@emb[:,a]; col 5000+a = tanh(s2[b]+t[a]); pad cols zeroed
__global__ void um2_kernel(const float* __restrict__ ust, const float* __restrict__ emb,
                           const float* __restrict__ s2, const float* __restrict__ t,
                           short* __restrict__ umb)
{
    const int b = blockIdx.y;
    __shared__ float us[64];
    if (threadIdx.x < 64) us[threadIdx.x] = ust[(size_t)b * F_ + threadIdx.x];
    __syncthreads();
    const int a = blockIdx.x * 256 + threadIdx.x;
    if (a < A_) {
        float acc = 0.f;
        #pragma unroll
        for (int g = 0; g < 64; ++g) acc += us[g] * emb[(size_t)g * A_ + a];
        umb[(size_t)b * KP2_ + a] = (short)f2bf(acc);
        umb[(size_t)b * KP2_ + A_ + a] = (short)f2bf(tanhf(s2[b] + t[a]));
    } else if (a < A_ + 48) {
        umb[(size_t)b * KP2_ + A_ + a] = 0;   // cols 10000..10047
    }
}

// zero pad columns of a bf16 buffer
__global__ void pad_kernel(short* __restrict__ buf, int ld, int c0, int n)
{
    const int b = blockIdx.x;
    for (int c = threadIdx.x; c < n; c += 64)
        buf[(size_t)b * ld + c0 + c] = 0;
}

// ---------------- launch ----------------
extern "C" void kernel_launch(void* const* d_in, const int* in_sizes, int n_in,
                              void* d_out, int out_size, void* d_ws, size_t ws_size,
                              hipStream_t stream)
{
    const float* x       = (const float*)d_in[0];
    const float* conv_w2 = (const float*)d_in[1];
    const float* conv_b2 = (const float*)d_in[2];
    const float* conv_w3 = (const float*)d_in[3];
    const float* conv_b3 = (const float*)d_in[4];
    const float* conv_w4 = (const float*)d_in[5];
    const float* conv_b4 = (const float*)d_in[6];
    const float* conv_w5 = (const float*)d_in[7];
    const float* conv_b5 = (const float*)d_in[8];
    const float* sc_fcl_w = (const float*)d_in[9];
    const float* sc_fcl_b = (const float*)d_in[10];
    const float* fic_fc_w = (const float*)d_in[11];
    const float* fic_fc_b = (const float*)d_in[12];
    const float* emb      = (const float*)d_in[13];
    const float* mlp_w1   = (const float*)d_in[14];
    const float* mlp_b1   = (const float*)d_in[15];
    const float* mlp_w2   = (const float*)d_in[16];
    const float* mlp_b2   = (const float*)d_in[17];
    const float* fic_fcl_w = (const float*)d_in[18];
    const float* fic_fcl_b = (const float*)d_in[19];
    const float* fusion_w  = (const float*)d_in[20];
    const float* fusion_b  = (const float*)d_in[21];
    const float* task_w    = (const float*)d_in[22];
    const float* task_b    = (const float*)d_in[23];

    float* ws = (float*)d_ws;
    short* xp     = (short*)(ws + OFF_XP);
    float* part   = ws + OFF_PART;
    short* wp     = (short*)(ws + OFF_WP);
    float* e      = ws + OFF_E;
    short* ebf    = (short*)(ws + OFF_EBF);
    short* umbf   = (short*)(ws + OFF_UMBF);
    short* ummfbf = (short*)(ws + OFF_UMMFBF);
    float* ust    = ws + OFF_UST;
    float* vB     = ws + OFF_VB;
    float* s2     = ws + OFF_S2;
    float* t      = ws + OFF_T;
    short* ufbf   = (short*)(ws + OFF_UFBF);
    float* out    = (float*)d_out;

    // 1-2. preps
    prep_x_kernel<<<dim3(LP_, B_), CP_, 0, stream>>>(x, xp);
    prep_w_kernel<<<(128*14*CP_ + 255)/256, 256, 0, stream>>>(conv_w2, conv_w3, conv_w4, conv_w5, wp);

    // 3. conv v2 -> e (fp32)
    conv_gemm2_kernel<<<dim3(B_, 4, 2), 512, 0, stream>>>(xp, wp, conv_b2, conv_b3, conv_b4, conv_b5, e);

    // 4. e -> bf16
    prep_u_kernel<<<(B_*D_ + 255)/256, 256, 0, stream>>>(e, D_, ebf, D_, D_);

    // 5-6. u_sc -> ufbf cols [0,5000)
    gemm2_kernel<<<dim3(79, 4), 512, 0, stream>>>(ebf, D_, sc_fcl_w, D_, A_, 2, part);
    reduce2_kernel<<<(B_*A_ + 255)/256, 256, 0, stream>>>(part, sc_fcl_b, nullptr, ufbf, A_, KP2_, 0, 4, 0);
    pad_kernel<<<B_, 64, 0, stream>>>(ufbf, KP2_, 2*A_, 48);

    // 7. ust (dedicated kernel, was the 134us bottleneck)
    ust_kernel<<<B_, 256, 0, stream>>>(e, fic_fc_w, fic_fc_b, ust);

    // 8-10. mlp collapse + um (bf16 direct)
    prep_kernel<<<1, 128, 0, stream>>>(mlp_w1, mlp_b1, mlp_w2, mlp_b2, ust, vB, s2);
    ta_kernel<<<(A_ + 255)/256, 256, 0, stream>>>(emb, vB, t);
    um2_kernel<<<dim3(20, B_), 256, 0, stream>>>(ust, emb, s2, t, umbf);

    // 11-12. u_fic = tanh(um @ fic_fcl_w^T + b) -> ufbf cols [5000,10000)
    gemm2_kernel<<<dim3(79, 8), 512, 0, stream>>>(umbf, KP2_, fic_fcl_w, 2*A_, A_, 20, part);
    reduce2_kernel<<<(B_*A_ + 255)/256, 256, 0, stream>>>(part, fic_fcl_b, nullptr, ufbf, A_, KP2_, A_, 8, 1);

    // 13-14. u_mmf = uf @ fusion_w^T + b -> ummfbf
    gemm2_kernel<<<dim3(79, 8), 512, 0, stream>>>(ufbf, KP2_, fusion_w, 2*A_, A_, 20, part);
    reduce2_kernel<<<(B_*A_ + 255)/256, 256, 0, stream>>>(part, fusion_b, nullptr, ummfbf, A_, KP1_, 0, 8, 0);
    pad_kernel<<<B_, 64, 0, stream>>>(ummfbf, KP1_, A_, 56);

    // 15-16. task = ummf @ task_w^T + b -> out (fp32)
    gemm2_kernel<<<dim3(79, 8), 512, 0, stream>>>(ummfbf, KP1_, task_w, A_, A_, 10, part);
    reduce2_kernel<<<(B_*A_ + 255)/256, 256, 0, stream>>>(part, task_b, out, nullptr, A_, A_, 0, 8, 0);
}

// Round 6
// 315.633 us; speedup vs baseline: 12.5926x; 1.0400x over previous
//
#include <hip/hip_runtime.h>
#include <math.h>

#define B_ 128
#define L_ 200
#define C_ 300
#define K_ 128
#define A_ 5000
#define F_ 64
#define D_ 512
#define CP_ 320      // padded C
#define LP_ 260      // padded L rows
#define NPAD_ 5056   // 79*64
#define KP2_ 10048   // 157*64 (padded 2A)
#define KP1_ 5056    // 79*64  (padded A)
#define ZMAX_ 12

typedef __attribute__((ext_vector_type(8))) short bf16x8;
typedef __attribute__((ext_vector_type(8))) short short8;
typedef __attribute__((ext_vector_type(4))) float f32x4;

#define MFMA(a,b,c) __builtin_amdgcn_mfma_f32_16x16x32_bf16(a,b,c,0,0,0)

static __device__ __forceinline__ unsigned short f2bf(float f) {
    unsigned u = __float_as_uint(f);
    unsigned r = (u + 0x7FFFu + ((u >> 16) & 1u)) >> 16;
    return (unsigned short)r;
}

// ---------------- workspace layout (float offsets) — ws is ~800MB, no aliasing --
#define OFF_XP     ((size_t)0)            // 5,324,800 floats (bf16 x padded)
#define OFF_WP     ((size_t)5324800)      // 286,720
#define OFF_E      ((size_t)5611520)      // 65,536
#define OFF_EBF    ((size_t)5677056)      // 16,384
#define OFF_UST    ((size_t)5693440)      // 8,192
#define OFF_VB     ((size_t)5701632)      // 64
#define OFF_S2     ((size_t)5701696)      // 128
#define OFF_UMBF   ((size_t)5701824)      // 643,072
#define OFF_UFBF   ((size_t)6344896)      // 643,072
#define OFF_UMMFBF ((size_t)6987968)      // 323,584
#define OFF_PART   ((size_t)7311552)      // 12*128*5056 = 7,766,016
// end = 15,077,568 floats = 60.3 MB

// ---------------- prep: x -> bf16 padded [128][260][320] ----------------
__global__ __launch_bounds__(320) void prep_x_kernel(const float* __restrict__ x, short* __restrict__ xp)
{
    const int row = blockIdx.x;
    const int b   = blockIdx.y;
    const int c   = threadIdx.x;
    float v = 0.f;
    if (row < L_ && c < C_) v = x[((size_t)b * L_ + row) * C_ + c];
    xp[((size_t)b * LP_ + row) * CP_ + c] = (short)f2bf(v);
}

// ---------------- prep: conv weights -> bf16 [br][k][tap][320] ----------------
__global__ void prep_w_kernel(const float* __restrict__ w2, const float* __restrict__ w3,
                              const float* __restrict__ w4, const float* __restrict__ w5,
                              short* __restrict__ wp)
{
    const int idx = blockIdx.x * 256 + threadIdx.x;
    if (idx >= 128 * 14 * CP_) return;
    int off, wsz; const float* src;
    if (idx < 81920)       { off = idx;          wsz = 2; src = w2; }
    else if (idx < 204800) { off = idx - 81920;  wsz = 3; src = w3; }
    else if (idx < 368640) { off = idx - 204800; wsz = 4; src = w4; }
    else                   { off = idx - 368640; wsz = 5; src = w5; }
    const int k   = off / (wsz * CP_);
    const int r   = off % (wsz * CP_);
    const int tap = r / CP_;
    const int c   = r % CP_;
    float v = 0.f;
    if (c < C_) v = src[((size_t)k * C_ + c) * wsz + tap];
    wp[idx] = (short)f2bf(v);
}

// ---------------- conv implicit-GEMM v3: reg-staged prefetch overlapping MFMA ----
// grid (b=128, br=4, nt=2), block 512 (8 waves: 4m x 2n)
__global__ __launch_bounds__(512) void conv_gemm3_kernel(
    const short* __restrict__ xp, const short* __restrict__ wp,
    const float* __restrict__ b2, const float* __restrict__ b3,
    const float* __restrict__ b4, const float* __restrict__ b5,
    float* __restrict__ e, short* __restrict__ ebf)
{
    const int b  = blockIdx.x;
    const int br = blockIdx.y;
    const int nt = blockIdx.z;
    const int wsz  = br + 2;
    const int Pout = 199 - br;
    const int wbase = (br == 0) ? 0 : (br == 1) ? 81920 : (br == 2) ? 204800 : 368640;

    const int tid  = threadIdx.x;
    const int wave = tid >> 6;
    const int lane = tid & 63;
    const int mw   = wave & 3;
    const int nw   = wave >> 2;

    __shared__ short lA[260 * 36];      // 18.7 KB
    __shared__ short lB[5 * 64 * 36];   // 23.0 KB
    __shared__ float smax[4][64];

    // chunk assignments (chunk = 16B of a 32-col slice)
    const int nbB = wsz * 256;
    const bool hA2 = (tid < 16);                 // A chunks: tid, tid+512, tid+1024(<1040)
    const bool hB1 = (tid + 512 < nbB);
    const bool hB2 = (tid + 1024 < nbB);

    const short* xbase = xp + (size_t)b * LP_ * CP_;
    const short* wpb   = wp + wbase + (size_t)(nt * 64) * (wsz * CP_);

    f32x4 acc[4][2];
    #pragma unroll
    for (int mf = 0; mf < 4; ++mf)
        #pragma unroll
        for (int nf = 0; nf < 2; ++nf)
            acc[mf][nf] = (f32x4){0.f, 0.f, 0.f, 0.f};

    short8 a0, a1, a2, bb0, bb1, bb2;

    // loaders for cc-slice
    #define LDA(ch, cc) (*(const short8*)(xbase + (size_t)((ch) >> 2) * CP_ + (cc) * 32 + ((ch) & 3) * 8))
    #define LDB(ch, cc) (*(const short8*)(wpb + (size_t)((((ch) & 255) >> 2)) * (wsz * CP_) + ((ch) >> 8) * CP_ + (cc) * 32 + (((ch) & 255) & 3) * 8))

    // prologue: load cc=0
    a0 = LDA(tid, 0); a1 = LDA(tid + 512, 0);
    if (hA2) a2 = LDA(tid + 1024, 0);
    bb0 = LDB(tid, 0);
    if (hB1) bb1 = LDB(tid + 512, 0);
    if (hB2) bb2 = LDB(tid + 1024, 0);

    for (int cc = 0; cc < 10; ++cc) {
        __syncthreads();   // prior MFMA reads done; staged regs complete (vmcnt drain)
        // store regs -> LDS
        {
            int ch = tid;        *(short8*)(lA + (ch >> 2) * 36 + (ch & 3) * 8) = a0;
            ch = tid + 512;      *(short8*)(lA + (ch >> 2) * 36 + (ch & 3) * 8) = a1;
            if (hA2) { ch = tid + 1024; *(short8*)(lA + (ch >> 2) * 36 + (ch & 3) * 8) = a2; }
            ch = tid;            *(short8*)(lB + (((ch >> 8) << 6) + ((ch & 255) >> 2)) * 36 + ((ch & 255) & 3) * 8) = bb0;
            if (hB1) { ch = tid + 512;  *(short8*)(lB + (((ch >> 8) << 6) + ((ch & 255) >> 2)) * 36 + ((ch & 255) & 3) * 8) = bb1; }
            if (hB2) { ch = tid + 1024; *(short8*)(lB + (((ch >> 8) << 6) + ((ch & 255) >> 2)) * 36 + ((ch & 255) & 3) * 8) = bb2; }
        }
        __syncthreads();   // LDS visible
        // issue next-slice loads: they fly during the MFMA section below
        if (cc + 1 < 10) {
            a0 = LDA(tid, cc + 1); a1 = LDA(tid + 512, cc + 1);
            if (hA2) a2 = LDA(tid + 1024, cc + 1);
            bb0 = LDB(tid, cc + 1);
            if (hB1) bb1 = LDB(tid + 512, cc + 1);
            if (hB2) bb2 = LDB(tid + 1024, cc + 1);
        }
        for (int tap = 0; tap < wsz; ++tap) {
            bf16x8 af[4], bfr[2];
            #pragma unroll
            for (int mf = 0; mf < 4; ++mf)
                af[mf] = *(const bf16x8*)(lA + (mw * 64 + mf * 16 + (lane & 15) + tap) * 36 + (lane >> 4) * 8);
            #pragma unroll
            for (int nf = 0; nf < 2; ++nf)
                bfr[nf] = *(const bf16x8*)(lB + (tap * 64 + nw * 32 + nf * 16 + (lane & 15)) * 36 + (lane >> 4) * 8);
            #pragma unroll
            for (int mf = 0; mf < 4; ++mf)
                #pragma unroll
                for (int nf = 0; nf < 2; ++nf)
                    acc[mf][nf] = MFMA(af[mf], bfr[nf], acc[mf][nf]);
        }
    }
    #undef LDA
    #undef LDB

    // epilogue: masked max over positions
    float vm0 = -1e30f, vm1 = -1e30f;
    #pragma unroll
    for (int mf = 0; mf < 4; ++mf) {
        const int rowbase = mw * 64 + mf * 16 + (lane >> 4) * 4;
        #pragma unroll
        for (int r = 0; r < 4; ++r) {
            const bool valid = (rowbase + r) < Pout;
            vm0 = fmaxf(vm0, valid ? acc[mf][0][r] : -1e30f);
            vm1 = fmaxf(vm1, valid ? acc[mf][1][r] : -1e30f);
        }
    }
    vm0 = fmaxf(vm0, __shfl_xor(vm0, 16)); vm0 = fmaxf(vm0, __shfl_xor(vm0, 32));
    vm1 = fmaxf(vm1, __shfl_xor(vm1, 16)); vm1 = fmaxf(vm1, __shfl_xor(vm1, 32));
    if (lane < 16) {
        smax[mw][nw * 32 + lane]      = vm0;
        smax[mw][nw * 32 + 16 + lane] = vm1;
    }
    __syncthreads();
    if (tid < 64) {
        const float m = fmaxf(fmaxf(smax[0][tid], smax[1][tid]), fmaxf(smax[2][tid], smax[3][tid]));
        const int k = nt * 64 + tid;
        const float* bp = (br == 0) ? b2 : (br == 1) ? b3 : (br == 2) ? b4 : b5;
        const float val = fmaxf(bp[k] + m, 0.f);
        e[(size_t)b * D_ + k * 4 + br] = val;
        ebf[(size_t)b * D_ + k * 4 + br] = (short)f2bf(val);
    }
}

// ---------------- big MFMA GEMM v3: loads issued after barrier, overlap MFMA ----
// grid (79, z), block 512 (8 waves: 4m x 2n), tile M=128 N=64
__global__ __launch_bounds__(512) void gemm3_kernel(
    const short* __restrict__ Abf, int Kpad,
    const float* __restrict__ W, int K, int N,
    int steps_per_z, float* __restrict__ partial)
{
    const int n0 = blockIdx.x * 64;
    const int total = Kpad >> 6;
    const int sbeg = blockIdx.y * steps_per_z;
    const int send = min(sbeg + steps_per_z, total);

    const int tid  = threadIdx.x;
    const int wave = tid >> 6;
    const int lane = tid & 63;
    const int mw   = wave & 3;
    const int nw   = wave >> 2;

    __shared__ short lA[128 * 68];
    __shared__ short lB[64 * 68];

    const int arow = tid >> 2, ac0 = (tid & 3) * 16;
    const int fil  = tid >> 3, wc0 = (tid & 7) * 8;

    f32x4 acc[2][2];
    #pragma unroll
    for (int mf = 0; mf < 2; ++mf)
        #pragma unroll
        for (int nf = 0; nf < 2; ++nf)
            acc[mf][nf] = (f32x4){0.f, 0.f, 0.f, 0.f};

    short8 ra0, ra1;
    float4 rw0, rw1;
    const bool wrow_ok = (n0 + fil) < N;

    {
        const int kb = sbeg * 64;
        ra0 = *(const short8*)(Abf + (size_t)arow * Kpad + kb + ac0);
        ra1 = *(const short8*)(Abf + (size_t)arow * Kpad + kb + ac0 + 8);
        rw0 = make_float4(0.f,0.f,0.f,0.f); rw1 = rw0;
        if (wrow_ok && (kb + wc0) < K)     rw0 = *(const float4*)(W + (size_t)(n0 + fil) * K + kb + wc0);
        if (wrow_ok && (kb + wc0 + 4) < K) rw1 = *(const float4*)(W + (size_t)(n0 + fil) * K + kb + wc0 + 4);
    }

    for (int s = sbeg; s < send; ++s) {
        __syncthreads();   // prior MFMA reads done + staged loads complete
        *(short8*)(lA + arow * 68 + ac0)     = ra0;
        *(short8*)(lA + arow * 68 + ac0 + 8) = ra1;
        {
            short8 wb;
            wb[0]=(short)f2bf(rw0.x); wb[1]=(short)f2bf(rw0.y); wb[2]=(short)f2bf(rw0.z); wb[3]=(short)f2bf(rw0.w);
            wb[4]=(short)f2bf(rw1.x); wb[5]=(short)f2bf(rw1.y); wb[6]=(short)f2bf(rw1.z); wb[7]=(short)f2bf(rw1.w);
            *(short8*)(lB + fil * 68 + wc0) = wb;
        }
        __syncthreads();   // LDS visible
        // issue next-phase loads AFTER the barrier: they overlap the MFMA below
        if (s + 1 < send) {
            const int kb = (s + 1) * 64;
            ra0 = *(const short8*)(Abf + (size_t)arow * Kpad + kb + ac0);
            ra1 = *(const short8*)(Abf + (size_t)arow * Kpad + kb + ac0 + 8);
            float4 t0 = make_float4(0.f,0.f,0.f,0.f), t1 = t0;
            if (wrow_ok && (kb + wc0) < K)     t0 = *(const float4*)(W + (size_t)(n0 + fil) * K + kb + wc0);
            if (wrow_ok && (kb + wc0 + 4) < K) t1 = *(const float4*)(W + (size_t)(n0 + fil) * K + kb + wc0 + 4);
            rw0 = t0; rw1 = t1;
        }
        #pragma unroll
        for (int ks = 0; ks < 2; ++ks) {
            bf16x8 af[2], bfr[2];
            #pragma unroll
            for (int mf = 0; mf < 2; ++mf)
                af[mf] = *(const bf16x8*)(lA + (mw * 32 + mf * 16 + (lane & 15)) * 68 + ks * 32 + (lane >> 4) * 8);
            #pragma unroll
            for (int nf = 0; nf < 2; ++nf)
                bfr[nf] = *(const bf16x8*)(lB + (nw * 32 + nf * 16 + (lane & 15)) * 68 + ks * 32 + (lane >> 4) * 8);
            #pragma unroll
            for (int mf = 0; mf < 2; ++mf)
                #pragma unroll
                for (int nf = 0; nf < 2; ++nf)
                    acc[mf][nf] = MFMA(af[mf], bfr[nf], acc[mf][nf]);
        }
    }

    #pragma unroll
    for (int mf = 0; mf < 2; ++mf)
        #pragma unroll
        for (int nf = 0; nf < 2; ++nf)
            #pragma unroll
            for (int r = 0; r < 4; ++r) {
                const int row = mw * 32 + mf * 16 + (lane >> 4) * 4 + r;
                const int col = nw * 32 + nf * 16 + (lane & 15);
                partial[((size_t)blockIdx.y * B_ + row) * NPAD_ + n0 + col] = acc[mf][nf][r];
            }
}

// ---------------- reduce partials + bias (+tanh) -> bf16/fp32, fused pad ------
__global__ void reduce2_kernel(const float* __restrict__ partial, const float* __restrict__ bias,
                               float* __restrict__ outf, short* __restrict__ outb,
                               int N, int ldo, int ooff, int js, int act, int padn)
{
    const int Ntot = N + padn;
    const int idx = blockIdx.x * 256 + threadIdx.x;
    if (idx >= B_ * Ntot) return;
    const int n = idx % Ntot;
    const int b = idx / Ntot;
    if (n >= N) { outb[(size_t)b * ldo + ooff + n] = 0; return; }
    float s = bias[n];
    for (int k = 0; k < js; ++k) s += partial[((size_t)k * B_ + b) * NPAD_ + n];
    if (act) s = tanhf(s);
    if (outb) outb[(size_t)b * ldo + ooff + n] = (short)f2bf(s);
    else      outf[(size_t)b * ldo + ooff + n] = s;
}

// ---------------- ust: (128,64) = e @ fic_fc_w^T + b ----------------
__global__ __launch_bounds__(256) void ust_kernel(
    const float* __restrict__ e, const float* __restrict__ W,
    const float* __restrict__ bias, float* __restrict__ ust)
{
    const int b = blockIdx.x;
    const int f = threadIdx.x >> 2;
    const int q = threadIdx.x & 3;
    const float* er = e + (size_t)b * D_ + q * 128;
    const float* wr = W + (size_t)f * D_ + q * 128;
    float acc = 0.f;
    #pragma unroll
    for (int j = 0; j < 128; j += 4) {
        const float4 ev = *(const float4*)(er + j);
        const float4 wv = *(const float4*)(wr + j);
        acc += ev.x*wv.x + ev.y*wv.y + ev.z*wv.z + ev.w*wv.w;
    }
    acc += __shfl_xor(acc, 1);
    acc += __shfl_xor(acc, 2);
    if (q == 0) ust[(size_t)b * F_ + f] = acc + bias[f];
}

// ---------------- tiny precompute: vA,vB,c,s2 ----------------
__global__ void prep_kernel(const float* __restrict__ mlp_w1, const float* __restrict__ mlp_b1,
                            const float* __restrict__ mlp_w2, const float* __restrict__ mlp_b2,
                            const float* __restrict__ ust,
                            float* __restrict__ vB, float* __restrict__ s2)
{
    __shared__ float vA[64];
    __shared__ float csh;
    const int tid = threadIdx.x;   // 128
    if (tid < 64) {
        float a = 0.f;
        for (int f = 0; f < 64; ++f) a += mlp_w2[f] * mlp_w1[f * 128 + tid];
        vA[tid] = a;
    } else {
        const int g = tid - 64;
        float bsum = 0.f;
        for (int f = 0; f < 64; ++f) bsum += mlp_w2[f] * mlp_w1[f * 128 + 64 + g];
        vB[g] = bsum;
    }
    if (tid == 0) {
        float c = mlp_b2[0];
        for (int f = 0; f < 64; ++f) c += mlp_b1[f] * mlp_w2[f];
        csh = c;
    }
    __syncthreads();
    float s = csh;
    const float* ub = ust + (size_t)tid * F_;
    for (int g = 0; g < 64; ++g) s += ub[g] * vA[g];
    s2[tid] = s;
}

// um bf16: col a = ust[b]@emb[:,a]; col 5000+a = tanh(s2[b] + vB@emb[:,a]); pads 0
__global__ void um3_kernel(const float* __restrict__ ust, const float* __restrict__ emb,
                           const float* __restrict__ s2, const float* __restrict__ vB,
                           short* __restrict__ umb)
{
    const int b = blockIdx.y;
    __shared__ float us[64];
    __shared__ float vb[64];
    if (threadIdx.x < 64) {
        us[threadIdx.x] = ust[(size_t)b * F_ + threadIdx.x];
        vb[threadIdx.x] = vB[threadIdx.x];
    }
    __syncthreads();
    const int a = blockIdx.x * 256 + threadIdx.x;
    if (a < A_) {
        float accm = 0.f, acct = 0.f;
        #pragma unroll
        for (int g = 0; g < 64; ++g) {
            const float ev = emb[(size_t)g * A_ + a];
            accm += us[g] * ev;
            acct += vb[g] * ev;
        }
        umb[(size_t)b * KP2_ + a] = (short)f2bf(accm);
        umb[(size_t)b * KP2_ + A_ + a] = (short)f2bf(tanhf(s2[b] + acct));
    } else if (a < A_ + 48) {
        umb[(size_t)b * KP2_ + A_ + a] = 0;   // cols 10000..10047
    }
}

// ---------------- launch ----------------
extern "C" void kernel_launch(void* const* d_in, const int* in_sizes, int n_in,
                              void* d_out, int out_size, void* d_ws, size_t ws_size,
                              hipStream_t stream)
{
    const float* x       = (const float*)d_in[0];
    const float* conv_w2 = (const float*)d_in[1];
    const float* conv_b2 = (const float*)d_in[2];
    const float* conv_w3 = (const float*)d_in[3];
    const float* conv_b3 = (const float*)d_in[4];
    const float* conv_w4 = (const float*)d_in[5];
    const float* conv_b4 = (const float*)d_in[6];
    const float* conv_w5 = (const float*)d_in[7];
    const float* conv_b5 = (const float*)d_in[8];
    const float* sc_fcl_w = (const float*)d_in[9];
    const float* sc_fcl_b = (const float*)d_in[10];
    const float* fic_fc_w = (const float*)d_in[11];
    const float* fic_fc_b = (const float*)d_in[12];
    const float* emb      = (const float*)d_in[13];
    const float* mlp_w1   = (const float*)d_in[14];
    const float* mlp_b1   = (const float*)d_in[15];
    const float* mlp_w2   = (const float*)d_in[16];
    const float* mlp_b2   = (const float*)d_in[17];
    const float* fic_fcl_w = (const float*)d_in[18];
    const float* fic_fcl_b = (const float*)d_in[19];
    const float* fusion_w  = (const float*)d_in[20];
    const float* fusion_b  = (const float*)d_in[21];
    const float* task_w    = (const float*)d_in[22];
    const float* task_b    = (const float*)d_in[23];

    float* ws = (float*)d_ws;
    short* xp     = (short*)(ws + OFF_XP);
    short* wp     = (short*)(ws + OFF_WP);
    float* e      = ws + OFF_E;
    short* ebf    = (short*)(ws + OFF_EBF);
    float* ust    = ws + OFF_UST;
    float* vB     = ws + OFF_VB;
    float* s2     = ws + OFF_S2;
    short* umbf   = (short*)(ws + OFF_UMBF);
    short* ufbf   = (short*)(ws + OFF_UFBF);
    short* ummfbf = (short*)(ws + OFF_UMMFBF);
    float* part   = ws + OFF_PART;
    float* out    = (float*)d_out;

    // 1-2. preps
    prep_x_kernel<<<dim3(LP_, B_), CP_, 0, stream>>>(x, xp);
    prep_w_kernel<<<(128*14*CP_ + 255)/256, 256, 0, stream>>>(conv_w2, conv_w3, conv_w4, conv_w5, wp);

    // 3. conv v3 -> e + ebf
    conv_gemm3_kernel<<<dim3(B_, 4, 2), 512, 0, stream>>>(xp, wp, conv_b2, conv_b3, conv_b4, conv_b5, e, ebf);

    // 4-5. u_sc -> ufbf cols [0,5000)
    gemm3_kernel<<<dim3(79, 4), 512, 0, stream>>>(ebf, D_, sc_fcl_w, D_, A_, 2, part);
    reduce2_kernel<<<(B_*A_ + 255)/256, 256, 0, stream>>>(part, sc_fcl_b, nullptr, ufbf, A_, KP2_, 0, 4, 0, 0);

    // 6. ust
    ust_kernel<<<B_, 256, 0, stream>>>(e, fic_fc_w, fic_fc_b, ust);

    // 7-8. mlp collapse + um (ta merged)
    prep_kernel<<<1, 128, 0, stream>>>(mlp_w1, mlp_b1, mlp_w2, mlp_b2, ust, vB, s2);
    um3_kernel<<<dim3(20, B_), 256, 0, stream>>>(ust, emb, s2, vB, umbf);

    // 9-10. u_fic -> ufbf cols [5000,10000) + pad [10000,10048)
    gemm3_kernel<<<dim3(79, 12), 512, 0, stream>>>(umbf, KP2_, fic_fcl_w, 2*A_, A_, 14, part);
    reduce2_kernel<<<(B_*(A_+48) + 255)/256, 256, 0, stream>>>(part, fic_fcl_b, nullptr, ufbf, A_, KP2_, A_, 12, 1, 48);

    // 11-12. u_mmf -> ummfbf + pad [5000,5056)
    gemm3_kernel<<<dim3(79, 12), 512, 0, stream>>>(ufbf, KP2_, fusion_w, 2*A_, A_, 14, part);
    reduce2_kernel<<<(B_*(A_+56) + 255)/256, 256, 0, stream>>>(part, fusion_b, nullptr, ummfbf, A_, KP1_, 0, 12, 0, 56);

    // 13-14. task -> out (fp32)
    gemm3_kernel<<<dim3(79, 12), 512, 0, stream>>>(ummfbf, KP1_, task_w, A_, A_, 7, part);
    reduce2_kernel<<<(B_*A_ + 255)/256, 256, 0, stream>>>(part, task_b, out, nullptr, A_, A_, 0, 12, 0, 0);
}